// Round 4
// baseline (3936.260 us; speedup 1.0000x reference)
//
#include <hip/hip_runtime.h>
#include <stdint.h>

#define B_  8
#define N_  256
#define DH_ 192
#define L_  2
#define G3  576
#define G6  1152
#define NW  4      // WGs per batch per role
#define DS  48     // d-slice per WG
#define KD  24     // H-history dwords per WG (48 bf16)
#define GC  288    // g-cols per WG
#define HSW 160    // u64 words per WG message slot (145 used, padded)
#define HSR (2 * 8 * NW * HSW)    // u64 per role (2 parities x 8 b x 4 w)
#define STH 10001  // H1 channel stamp base
#define STP 20001  // PRE channel stamp base
#define STQ 25001  // xq channel stamp base
#define SPK 50000  // prepack done
#define SF1 50001  // fc1 done
#define SF2 50002  // PRE done
#define SDN 60001  // scan done

typedef unsigned long long u64;

__device__ __forceinline__ float bflo(uint32_t u) { return __uint_as_float(u << 16); }
__device__ __forceinline__ float bfhi(uint32_t u) { return __uint_as_float(u & 0xffff0000u); }
__device__ __forceinline__ uint32_t f2bf(float f) {
    uint32_t x = __float_as_uint(f);
    x += 0x7fffu + ((x >> 16) & 1u);          // RNE
    return x >> 16;
}
__device__ __forceinline__ float sigm(float x)  { return 1.f / (1.f + __expf(-x)); }
__device__ __forceinline__ float tanhf_(float x){ return 1.f - 2.f / (1.f + __expf(2.f * x)); }
__device__ __forceinline__ u64 packvs(float v, int st) {
    return ((u64)(uint32_t)st << 32) | __float_as_uint(v);
}
__device__ __forceinline__ u64 agload(const u64* p) {
    return __hip_atomic_load(p, __ATOMIC_RELAXED, __HIP_MEMORY_SCOPE_AGENT);
}
__device__ __forceinline__ void agstore(u64* p, u64 v) {
    __hip_atomic_store(p, v, __ATOMIC_RELAXED, __HIP_MEMORY_SCOPE_AGENT);
}
__device__ __forceinline__ float u2f(u64 v) { return __uint_as_float((uint32_t)v); }

// ---------------------------------------------------------------------------
// LDS layouts. Scan: wr (own 48 d x full 192 k, padded stride 49) + full
// exchanged state (hn/su0/su1 of all 4 WGs) + reconstructed v0/v1.
// Gc fused weights (Wf = Wcomb@wr, own 288 cols x 192 k) live in registers.
// ---------------------------------------------------------------------------
struct ScanSm {
    uint32_t wrS[192 * 49];          // 37,632 B  (wr0|wr1 bf16 pair at [k*49+d])
    float sV0[DH_], sV1[DH_];
    float sHnF[DH_], sSu0f[DH_], sSu1f[DH_];
    float sA0[N_], sA1[N_];
    float sKsc[N_];
    float sAdjN[N_], sSmN[N_];
    float sXq[2][DH_];
    float sPre[6 * DS], sXv[DS];
    float sGc[GC], sMv[DS], sHn[DS];
    float su0[DS], su1[DS];
    float sRedS[8], sRedX[4], sKdP[4], sSaved[8], sSavedA[2], sSavedS[2];
};
struct WorkSm {
    float sX[DH_];
    float sPv[GC];
    float sRed[3];
};
struct PrologSm {
    float sA[8][768];
    float sRed[3][8][192];
};
struct MlpSm {
    float sH[8][576];
    float sRed[3][8][192];
    float sT[8][192];
};
union SmemAll { ScanSm s; WorkSm w; PrologSm p; MlpSm m; };

// ---------------------------------------------------------------------------
// Prepack slice: WpreT, worker weights Wp4w, M-step weights Wr4 (new layout
// [l][w][k*48+dl]), biasPre, gbx.
// ---------------------------------------------------------------------------
__device__ void prepack_slice(int idx,
    const float* __restrict__ wr0, const float* __restrict__ wr1,
    const float* __restrict__ c_wih, const float* __restrict__ c_whh,
    const float* __restrict__ c_bih, const float* __restrict__ c_bhh,
    const float* __restrict__ p_wih, const float* __restrict__ p_whh,
    const float* __restrict__ p_bih, const float* __restrict__ p_bhh,
    float* __restrict__ WpreT, uint32_t* __restrict__ Wr4,
    uint32_t* __restrict__ Wp4w,
    float* __restrict__ biasPre, float* __restrict__ gbx)
{
    for (int l = 0; l < L_; ++l) {
        const float* cwih = c_wih + l * G3 * DH_;
        const float* pwhh = p_whh + l * G3 * DH_;
        if (l == 0) {
            int k = idx / G6, r = idx - k * G6;
            float w = (r < G3) ? cwih[r * DH_ + k] : pwhh[(r - G3) * DH_ + k];
            WpreT[k * G6 + r] = w;
        }
        if (l == 1 && idx < NW * 27648) {
            int w = idx / 27648, pos = idx % 27648;
            int p4 = pos / 1152, rem = pos % 1152;
            int c2 = rem >> 2, s = rem & 3;
            int p = 4 * p4 + s;
            int j = c2 / DS, dd = c2 % DS;
            int r = 192 * j + DS * w + dd;
            float v0 = (r < G3) ? cwih[r * DH_ + 2 * p]     : pwhh[(r - G3) * DH_ + 2 * p];
            float v1 = (r < G3) ? cwih[r * DH_ + 2 * p + 1] : pwhh[(r - G3) * DH_ + 2 * p + 1];
            Wp4w[idx] = f2bf(v0) | (f2bf(v1) << 16);
        }
        if (idx < NW * 9216) {
            int w = idx / 9216, pos = idx % 9216;
            int k = pos / 48, dl = pos % 48;
            int d = w * DS + dl;
            Wr4[l * NW * 9216 + idx] =
                f2bf(wr0[l * DH_ * DH_ + d * DH_ + k]) |
                (f2bf(wr1[l * DH_ * DH_ + d * DH_ + k]) << 16);
        }
        if (idx < G6) {
            float base = (idx < G3) ? c_bih[l * G3 + idx] : p_bhh[l * G3 + idx - G3];
            float fold = 0.f;
            if (idx < 384)                    fold = c_bhh[l * G3 + idx];
            else if (idx >= G3 && idx < 960)  fold = p_bih[l * G3 + idx - G3];
            biasPre[l * G6 + idx] = base + fold;
        }
        if (idx < 384) {
            gbx[l * 384 + idx] = (idx < DH_) ? c_bhh[l * G3 + 384 + idx]
                                             : p_bih[l * G3 + 384 + (idx - DH_)];
        }
    }
}

// ---------------------------------------------------------------------------
// Fused Gc weights: Wf{0,1} = [cwhh; pwih] @ wr{0,1}  (1152 x 192, bf16 pairs).
// Layout: WfG[(l*NW + wdst)*288*192 + c2*192 + mat*96 + k/2]  (u32 pairs).
// One 48-col tile per WG; 16 k-outputs per thread.
// ---------------------------------------------------------------------------
__device__ void wf_tile(int wgid, int t,
    const float* __restrict__ wr0, const float* __restrict__ wr1,
    const float* __restrict__ c_whh, const float* __restrict__ p_wih,
    uint32_t* __restrict__ WfG)
{
    const int jj = t / 12, kblk = t % 12;
    const int job = wgid * 48 + jj;            // 0..4607 = L*2*1152
    const int l = job / 2304, r = job % 2304;
    const int mat = r / 1152, cg = r % 1152;
    const float* wcp = (cg < G3) ? (c_whh + (size_t)(l * G3 + cg) * DH_)
                                 : (p_wih + (size_t)(l * G3 + cg - G3) * DH_);
    const float* wrp = (mat == 0 ? wr0 : wr1) + (size_t)l * DH_ * DH_;
    const int k0 = kblk * 16;
    float acc[16];
    #pragma unroll
    for (int z = 0; z < 16; ++z) acc[z] = 0.f;
    for (int d = 0; d < DH_; ++d) {
        const float wc = wcp[d];
        const float* wrd = wrp + (size_t)d * DH_ + k0;
        #pragma unroll
        for (int z = 0; z < 16; ++z) acc[z] = fmaf(wc, wrd[z], acc[z]);
    }
    const int wdst = (cg % 192) / 48;
    const int c2 = (cg / 192) * 48 + (cg % 48);
    uint32_t* dst = WfG + (((size_t)l * NW + wdst) * 288 + c2) * 192 + mat * 96 + (k0 >> 1);
    #pragma unroll
    for (int z = 0; z < 8; ++z)
        dst[z] = f2bf(acc[2 * z]) | (f2bf(acc[2 * z + 1]) << 16);
}

// ---------------------------------------------------------------------------
// Global sync among the 96 co-resident WGs via stamped flags.
// ---------------------------------------------------------------------------
__device__ void flag_sync(u64* flags, int wgid, int t, int stamp)
{
    __threadfence();
    __syncthreads();
    if (t == 0) agstore(&flags[wgid], packvs(0.f, stamp));
    if (t < 96) {
        while ((uint32_t)(agload(&flags[t]) >> 32) != (uint32_t)stamp) {}
    }
    __syncthreads();
    __threadfence();
    __syncthreads();
}

// ---------------------------------------------------------------------------
// Prologue: fc1 then PRE-l1. Unchanged.
// ---------------------------------------------------------------------------
__device__ void prologue(char* smem, int wgid, int t,
    const float* __restrict__ features, const float* __restrict__ fc1_w,
    const float* __restrict__ fc1_b, const float* __restrict__ WpreT,
    const float* __restrict__ biasPre,
    float* __restrict__ Hcat, float* __restrict__ PREg, u64* __restrict__ Fp)
{
    PrologSm* P = (PrologSm*)smem;
    const int c = t % 192, kg = t / 192;
    for (int tt = wgid; tt < 256; tt += 96) {
        const int r0 = tt * 8;
        for (int q = t; q < 1536; q += 576) {
            int r = q / 192, c4 = q % 192;
            *(float4*)&P->sA[r][4 * c4] = *(const float4*)(features + (size_t)(r0 + r) * 768 + 4 * c4);
        }
        __syncthreads();
        {
            const float* bp = fc1_w + (size_t)(kg * 256) * 192 + c;
            float acc[8] = {0.f, 0.f, 0.f, 0.f, 0.f, 0.f, 0.f, 0.f};
            #pragma unroll 8
            for (int kk = 0; kk < 256; ++kk) {
                float bv = bp[(size_t)kk * 192];
                #pragma unroll
                for (int rr = 0; rr < 8; ++rr) acc[rr] += P->sA[rr][kg * 256 + kk] * bv;
            }
            #pragma unroll
            for (int rr = 0; rr < 8; ++rr) P->sRed[kg][rr][c] = acc[rr];
        }
        __syncthreads();
        if (t < 192) {
            float bv = fc1_b[t];
            #pragma unroll
            for (int rr = 0; rr < 8; ++rr) {
                float v = P->sRed[0][rr][t] + P->sRed[1][rr][t] + P->sRed[2][rr][t] + bv;
                Hcat[(size_t)(r0 + rr) * G3 + t] = fmaxf(v, 0.f);
            }
        }
        __syncthreads();
    }
    flag_sync(Fp + 96, wgid, t, SF1);
    {
        const float bpa = biasPre[t], bpb = biasPre[576 + t];
        for (int tt = wgid; tt < 256; tt += 96) {
            const int r0 = tt * 8;
            for (int q = t; q < 384; q += 576) {
                int r = q / 48, c4 = q % 48;
                *(float4*)&P->sA[r][4 * c4] = *(const float4*)(Hcat + (size_t)(r0 + r) * G3 + 4 * c4);
            }
            __syncthreads();
            {
                const float* b0 = WpreT + t;
                float a0[8] = {0.f,0.f,0.f,0.f,0.f,0.f,0.f,0.f};
                float a1[8] = {0.f,0.f,0.f,0.f,0.f,0.f,0.f,0.f};
                #pragma unroll 4
                for (int k = 0; k < 192; ++k) {
                    float bva = b0[(size_t)k * G6];
                    float bvb = b0[(size_t)k * G6 + 576];
                    #pragma unroll
                    for (int rr = 0; rr < 8; ++rr) {
                        float av = P->sA[rr][k];
                        a0[rr] += av * bva; a1[rr] += av * bvb;
                    }
                }
                #pragma unroll
                for (int rr = 0; rr < 8; ++rr) {
                    PREg[(size_t)(r0 + rr) * G6 + t]       = a0[rr] + bpa;
                    PREg[(size_t)(r0 + rr) * G6 + 576 + t] = a1[rr] + bpb;
                }
            }
            __syncthreads();
        }
    }
    flag_sync(Fp + 192, wgid, t, SF2);
}

// ---------------------------------------------------------------------------
// Epilogue: 3-layer MLP head. Unchanged.
// ---------------------------------------------------------------------------
__device__ void mlp_tail(char* smem, int wgid, int t,
    const float* __restrict__ Hcat,
    const float* __restrict__ mw0, const float* __restrict__ mb0,
    const float* __restrict__ mw1, const float* __restrict__ mb1,
    const float* __restrict__ mw2, const float* __restrict__ mb2,
    float* __restrict__ out, u64* __restrict__ Fd)
{
    if (t < 64) {
        while ((uint32_t)(agload(&Fd[t]) >> 32) != (uint32_t)SDN) {}
    }
    __syncthreads();
    __threadfence();
    __syncthreads();
    MlpSm* M = (MlpSm*)smem;
    const int c = t % 192, kg = t / 192;
    for (int tt = wgid; tt < 256; tt += 96) {
        const int r0 = tt * 8;
        for (int q = t; q < 1152; q += 576) {
            int r = q / 144, c4 = q % 144;
            *(float4*)&M->sH[r][4 * c4] = *(const float4*)(Hcat + (size_t)(r0 + r) * G3 + 4 * c4);
        }
        __syncthreads();
        {
            const float* bp = mw0 + (size_t)(kg * 192) * 192 + c;
            float acc[8] = {0.f,0.f,0.f,0.f,0.f,0.f,0.f,0.f};
            #pragma unroll 8
            for (int kk = 0; kk < 192; ++kk) {
                float bv = bp[(size_t)kk * 192];
                #pragma unroll
                for (int rr = 0; rr < 8; ++rr) acc[rr] += M->sH[rr][kg * 192 + kk] * bv;
            }
            #pragma unroll
            for (int rr = 0; rr < 8; ++rr) M->sRed[kg][rr][c] = acc[rr];
        }
        __syncthreads();
        if (t < 192) {
            float bv = mb0[t];
            #pragma unroll
            for (int rr = 0; rr < 8; ++rr)
                M->sT[rr][t] = fmaxf(M->sRed[0][rr][t] + M->sRed[1][rr][t] + M->sRed[2][rr][t] + bv, 0.f);
        }
        __syncthreads();
        {
            const float* bp = mw1 + (size_t)(kg * 64) * 192 + c;
            float acc[8] = {0.f,0.f,0.f,0.f,0.f,0.f,0.f,0.f};
            #pragma unroll 8
            for (int kk = 0; kk < 64; ++kk) {
                float bv = bp[(size_t)kk * 192];
                #pragma unroll
                for (int rr = 0; rr < 8; ++rr) acc[rr] += M->sT[rr][kg * 64 + kk] * bv;
            }
            #pragma unroll
            for (int rr = 0; rr < 8; ++rr) M->sRed[kg][rr][c] = acc[rr];
        }
        __syncthreads();
        if (t < 192) {
            float bv = mb1[t];
            #pragma unroll
            for (int rr = 0; rr < 8; ++rr)
                M->sH[rr][t] = fmaxf(M->sRed[0][rr][t] + M->sRed[1][rr][t] + M->sRed[2][rr][t] + bv, 0.f);
        }
        __syncthreads();
        {
            const float* bp = mw2 + (size_t)(kg * 64) * 192 + c;
            float acc[8] = {0.f,0.f,0.f,0.f,0.f,0.f,0.f,0.f};
            #pragma unroll 8
            for (int kk = 0; kk < 64; ++kk) {
                float bv = bp[(size_t)kk * 192];
                #pragma unroll
                for (int rr = 0; rr < 8; ++rr) acc[rr] += M->sH[rr][kg * 64 + kk] * bv;
            }
            #pragma unroll
            for (int rr = 0; rr < 8; ++rr) M->sRed[kg][rr][c] = acc[rr];
        }
        __syncthreads();
        if (t < 192) {
            float bv = mb2[t];
            #pragma unroll
            for (int rr = 0; rr < 8; ++rr)
                out[(size_t)(r0 + rr) * 192 + t] =
                    M->sRed[0][rr][t] + M->sRed[1][rr][t] + M->sRed[2][rr][t] + bv;
        }
        __syncthreads();
    }
}

// ---------------------------------------------------------------------------
// Scan body — raw-state exchange (hn/su0/su1/kd = 145 u64 per WG per step),
// single one-word-per-thread poll, fused Wf Gc matvec behind the poll.
// Parity double-buffer: overwrite of buf[p] at stamp i needs siblings'
// stamp-(i-1) messages, which need their stamp-(i-2) poll pass -> safe.
// ---------------------------------------------------------------------------
template<int ISL2>
__device__ void scan_body(
    ScanSm* S, int b, int w, int t,
    const float* __restrict__ xin, float* __restrict__ hout,
    const float* __restrict__ PREg, const float* __restrict__ adj,
    const float* __restrict__ smask,
    const uint32_t* __restrict__ WfGl, const uint32_t* __restrict__ Wr4l,
    const float* __restrict__ gbxl, const float* __restrict__ gatwl,
    uint32_t* __restrict__ Hw, u64* __restrict__ HSrole,
    u64* __restrict__ HcW, const u64* __restrict__ HcR,
    const u64* __restrict__ PREcR, const u64* __restrict__ XQcR,
    float* __restrict__ AsB, int sbase)
{
    const int lane = t & 63, wave = t >> 6;
    const int dg0 = w * DS;
    const float* adjB = adj   + (size_t)b * N_ * N_;
    const float* smB  = smask + (size_t)b * N_ * N_;
    const int cB4 = t >> 1, khB4 = t & 1;

    // wr (M-step) -> LDS [k*49 + dl]
    {
        const uint32_t* wrG = Wr4l + (size_t)w * 9216;
        for (int q = t; q < 9216; q += 576) {
            int k = q / 48, dl = q - 48 * k;
            S->wrS[k * 49 + dl] = wrG[q];
        }
    }
    // fused Gc weights -> registers (own 288 cols, per-thread half-k)
    uint4 wfreg[24];
    {
        const uint4* wfb = (const uint4*)(WfGl + ((size_t)w * 288 + cB4) * 192);
        #pragma unroll
        for (int p4 = 0; p4 < 12; ++p4) {
            wfreg[p4]      = wfb[khB4 * 12 + p4];
            wfreg[12 + p4] = wfb[24 + khB4 * 12 + p4];
        }
    }
    float wqx = (!ISL2 && t >= 192 && t < 384) ? gatwl[t - 192] : 0.f;
    float wkv = 0.f, g2b = 0.f, g5b = 0.f;
    if (t < DS) { wkv = gatwl[DH_ + dg0 + t]; g2b = gbxl[dg0 + t]; g5b = gbxl[DH_ + dg0 + t]; }
    if (t < N_) { S->sKsc[t] = 0.f; S->sA0[t] = 0.f; S->sA1[t] = 0.f; }
    if (t < DS) { S->su0[t] = 0.f; S->su1[t] = 0.f; }
    if (t < 8)  S->sRedS[t] = 0.f;
    if (w == 0 && t < N_) AsB[t] = 0.f;

    u64* myHS0 = HSrole + ((size_t)b * NW + w) * HSW;   // parity 0

    if (!ISL2) {
        if (t < DS) {
            const float* pre = PREg + (size_t)(b * N_) * G6 + dg0 + t;
            S->sPre[t] = pre[0]; S->sPre[DS + t] = pre[192]; S->sPre[2 * DS + t] = pre[384];
            S->sPre[3 * DS + t] = pre[576]; S->sPre[4 * DS + t] = pre[768]; S->sPre[5 * DS + t] = pre[960];
            S->sXv[t] = xin[(size_t)(b * N_) * G3 + dg0 + t];
        }
        for (int q = t; q < 224; q += 576) {
            if (q < 64)       *(float4*)&S->sAdjN[4 * q] = *(const float4*)(adjB + N_ + 4 * q);
            else if (q < 128) { int q2 = q - 64;  *(float4*)&S->sSmN[4 * q2] = *(const float4*)(smB + N_ + 4 * q2); }
            else if (q < 176) { int q2 = q - 128; *(float4*)&S->sXq[1][4 * q2] = *(const float4*)(xin + (size_t)(b * N_ + 1) * G3 + 4 * q2); }
            else              { int q2 = q - 176; *(float4*)&S->sXq[0][4 * q2] = *(const float4*)(xin + (size_t)(b * N_ + 2) * G3 + 4 * q2); }
        }
    } else {
        for (int q = t; q < 321; q += 576) {
            if (q < 64)       *(float4*)&S->sAdjN[4 * q] = *(const float4*)(adjB + N_ + 4 * q);
            else if (q < 128) { int q2 = q - 64;  *(float4*)&S->sSmN[4 * q2] = *(const float4*)(smB + N_ + 4 * q2); }
            else if (q < 176) {
                int d = q - 128;
                const u64* p = HcR + ((size_t)(b * N_) * NW + w) * DS + d;
                u64 v; do { v = agload(p); } while ((uint32_t)(v >> 32) != (uint32_t)STH);
                S->sXv[d] = __uint_as_float((uint32_t)v);
            } else if (q < 320) {
                int qq = q - 176;
                const u64* p = PREcR + ((size_t)(b * N_) * NW + w) * 144 + qq;
                u64 v; do { v = agload(p); } while ((uint32_t)(v >> 32) != (uint32_t)STP);
                uint32_t pl = (uint32_t)v;
                S->sPre[2 * qq] = bflo(pl); S->sPre[2 * qq + 1] = bfhi(pl);
            } else {
                const u64* p = XQcR + b * N_ + 1;
                u64 v; do { v = agload(p); } while ((uint32_t)(v >> 32) != (uint32_t)(STQ + 1));
                S->sSaved[3] = __uint_as_float((uint32_t)v);
            }
        }
    }
    __syncthreads();
    // ---- step 0 (no attention) ----
    {
        float hn = 0.f;
        if (t < DS) {
            float xv = S->sXv[t];
            float r1 = sigm(S->sPre[t]), z1 = sigm(S->sPre[DS + t]);
            float n1 = tanhf_(S->sPre[2 * DS + t] + r1 * g2b);
            float Cv = (1.f - z1) * n1;
            float r2 = sigm(S->sPre[3 * DS + t]), z2 = sigm(S->sPre[4 * DS + t]);
            float n2 = tanhf_(g5b + r2 * S->sPre[5 * DS + t]);
            hn = Cv + (1.f - z2) * n2 + z2 * xv;
            S->sHn[t] = hn;
            hout[(size_t)(b * N_) * G3 + dg0 + t] = hn;
            if (!ISL2) HcW[((size_t)(b * N_) * NW + w) * DS + t] = packvs(hn, STH);
            agstore(myHS0 + t, packvs(hn, sbase));
        }
        if (t == 0) { S->sSavedA[0] = S->sAdjN[0]; S->sSavedS[0] = S->sSmN[0]; }
        if (t < 96) agstore(myHS0 + 48 + t, packvs(0.f, sbase));
        if (wave == 0) {
            float v = hn * wkv;
            #pragma unroll
            for (int o = 32; o; o >>= 1) v += __shfl_xor(v, o);
            if (lane == 0) { S->sSaved[6] = v; agstore(myHS0 + 144, packvs(v, sbase)); }
        }
    }
    __syncthreads();
    if (t < KD) Hw[(size_t)t * N_] = f2bf(S->sHn[2 * t]) | (f2bf(S->sHn[2 * t + 1]) << 16);
    if (!ISL2 && t >= 192 && t < 384) {
        float px = S->sXq[1][t - 192] * wqx;
        #pragma unroll
        for (int o = 32; o; o >>= 1) px += __shfl_xor(px, o);
        if (lane == 0) S->sRedX[wave - 3] = px;
    }
    __syncthreads();
    float xqc = ISL2 ? S->sSaved[3] : (S->sRedX[0] + S->sRedX[1] + S->sRedX[2]);

    for (int i = 1; i < N_; ++i) {
        const int row = b * N_ + i;
        const int stamp = sbase + i;
        const int mpar = (i - 1) & 1, sp = i & 1;
        u64* myHS = HSrole + ((size_t)(sp * 8 + b) * NW + w) * HSW;

        // ---- PhA: one-word-per-thread poll || prefetch ----------------------
        if (t < 435) {
            const int sib = t / 145, idx = t - sib * 145;
            const int wsrc = (w + 1 + sib) & 3;
            const u64* p = HSrole + ((size_t)(mpar * 8 + b) * NW + wsrc) * HSW + idx;
            const uint32_t ex = (uint32_t)(stamp - 1);
            u64 v; do { v = agload(p); } while ((uint32_t)(v >> 32) != ex);
            float f = u2f(v);
            if (idx < 48)       S->sHnF[wsrc * DS + idx]        = f;
            else if (idx < 96)  S->sSu0f[wsrc * DS + idx - 48]  = f;
            else if (idx < 144) S->sSu1f[wsrc * DS + idx - 96]  = f;
            else                S->sKdP[sib] = f;
        } else {
            const int u = t - 435;
            const int inx = (i + 1 < N_) ? i + 1 : N_ - 1;
            if (!ISL2) {
                const int ixq = (i + 2 < N_) ? i + 2 : N_ - 1;
                for (int qq = u; qq < 260; qq += 141) {
                    if (qq < 64)
                        *(float4*)&S->sAdjN[4 * qq] = *(const float4*)(adjB + (size_t)inx * N_ + 4 * qq);
                    else if (qq < 128) { int q2 = qq - 64;
                        *(float4*)&S->sSmN[4 * q2] = *(const float4*)(smB + (size_t)inx * N_ + 4 * q2); }
                    else if (qq < 140) { int q2 = qq - 128;
                        *(float4*)&S->sXv[4 * q2] = *(const float4*)(xin + (size_t)row * G3 + dg0 + 4 * q2); }
                    else if (qq < 212) { int q2 = qq - 140; int g = q2 / 12, o = q2 - 12 * g;
                        *(float4*)&S->sPre[g * DS + 4 * o] =
                            *(const float4*)(PREg + (size_t)row * G6 + g * DH_ + dg0 + 4 * o); }
                    else { int q2 = qq - 212;
                        *(float4*)&S->sXq[i & 1][4 * q2] = *(const float4*)(xin + (size_t)(b * N_ + ixq) * G3 + 4 * q2); }
                }
            } else {
                for (int qq = u; qq < 321; qq += 141) {
                    if (qq < 64)
                        *(float4*)&S->sAdjN[4 * qq] = *(const float4*)(adjB + (size_t)inx * N_ + 4 * qq);
                    else if (qq < 128) { int q2 = qq - 64;
                        *(float4*)&S->sSmN[4 * q2] = *(const float4*)(smB + (size_t)inx * N_ + 4 * q2); }
                    else if (qq < 176) {
                        int d = qq - 128;
                        const u64* p = HcR + ((size_t)row * NW + w) * DS + d;
                        u64 v; do { v = agload(p); } while ((uint32_t)(v >> 32) != (uint32_t)(STH + i));
                        S->sXv[d] = __uint_as_float((uint32_t)v);
                    } else if (qq < 320) {
                        int q2 = qq - 176;
                        const u64* p = PREcR + ((size_t)row * NW + w) * 144 + q2;
                        u64 v; do { v = agload(p); } while ((uint32_t)(v >> 32) != (uint32_t)(STP + i));
                        uint32_t pl = (uint32_t)v;
                        S->sPre[2 * q2] = bflo(pl); S->sPre[2 * q2 + 1] = bfhi(pl);
                    } else {
                        const int inq = (i + 1 < N_) ? i + 1 : N_ - 1;
                        const u64* p = XQcR + b * N_ + inq;
                        u64 v; do { v = agload(p); } while ((uint32_t)(v >> 32) != (uint32_t)(STQ + inq));
                        S->sSaved[3] = __uint_as_float((uint32_t)v);
                    }
                }
            }
        }
        __syncthreads();                                         // B1

        // ---- merged: scalars (redundant) + v-build + AsB + xq(i+1) ---------
        {
            const float kdot = S->sKdP[0] + S->sKdP[1] + S->sKdP[2] + S->sSaved[6];
            const float e1 = (S->sSavedA[0] > 0.5f) ? __expf(xqc + kdot) : 0.f;
            const float Ssum = S->sRedS[0] + S->sRedS[1] + S->sRedS[2] + S->sRedS[3] + e1;
            const float invS = 1.f / Ssum;
            const float e1c0 = e1 * S->sSavedS[0], e1c1 = e1 - e1c0;
            if (t == 575) S->sKsc[i - 1] = kdot;
            if (t < 192) {
                const bool own = (t >= dg0) && (t < dg0 + DS);
                const int tl = t - dg0;
                const float hv = own ? S->sHn[tl] : S->sHnF[t];
                const float s0 = own ? S->su0[tl] : S->sSu0f[t];
                const float s1 = own ? S->su1[tl] : S->sSu1f[t];
                S->sV0[t] = (s0 + e1c0 * hv) * invS;
                S->sV1[t] = (s1 + e1c1 * hv) * invS;
            } else if (!ISL2 && t < 384) {
                float px = S->sXq[(i - 1) & 1][t - 192] * wqx;
                #pragma unroll
                for (int o = 32; o; o >>= 1) px += __shfl_xor(px, o);
                if (lane == 0) S->sRedX[wave - 3] = px;
            }
            if (w == 0) {
                if (t < 192) {
                    if (t < i) AsB[(size_t)i * N_ + t] =
                        (t < i - 1) ? (S->sA0[t] + S->sA1[t]) * invS : e1 * invS;
                } else if (t >= 448 && t < 512) {
                    const int jj = t - 256;
                    if (jj < i) AsB[(size_t)i * N_ + jj] =
                        (jj < i - 1) ? (S->sA0[jj] + S->sA1[jj]) * invS : e1 * invS;
                }
            }
        }
        __syncthreads();                                         // B2

        // ---- PhD: Gc = Wf0.v0 + Wf1.v1 (regs); M = wr.v (LDS, t<192) -------
        {
            float g = 0.f;
            const int vb = 96 * khB4;
            #pragma unroll
            for (int p4 = 0; p4 < 12; ++p4) {
                const uint4 wv = wfreg[p4];
                const float4 va = *(const float4*)&S->sV0[vb + 8 * p4];
                const float4 vc = *(const float4*)&S->sV0[vb + 8 * p4 + 4];
                g = fmaf(bflo(wv.x), va.x, g); g = fmaf(bfhi(wv.x), va.y, g);
                g = fmaf(bflo(wv.y), va.z, g); g = fmaf(bfhi(wv.y), va.w, g);
                g = fmaf(bflo(wv.z), vc.x, g); g = fmaf(bfhi(wv.z), vc.y, g);
                g = fmaf(bflo(wv.w), vc.z, g); g = fmaf(bfhi(wv.w), vc.w, g);
            }
            #pragma unroll
            for (int p4 = 0; p4 < 12; ++p4) {
                const uint4 wv = wfreg[12 + p4];
                const float4 va = *(const float4*)&S->sV1[vb + 8 * p4];
                const float4 vc = *(const float4*)&S->sV1[vb + 8 * p4 + 4];
                g = fmaf(bflo(wv.x), va.x, g); g = fmaf(bfhi(wv.x), va.y, g);
                g = fmaf(bflo(wv.y), va.z, g); g = fmaf(bfhi(wv.y), va.w, g);
                g = fmaf(bflo(wv.z), vc.x, g); g = fmaf(bfhi(wv.z), vc.y, g);
                g = fmaf(bflo(wv.w), vc.z, g); g = fmaf(bfhi(wv.w), vc.w, g);
            }
            g += __shfl_xor(g, 1);
            if (khB4 == 0) S->sGc[cB4] = g;
            if (t < 192) {
                const int d = t >> 2, q = t & 3;
                float m = 0.f;
                #pragma unroll 8
                for (int kk = 0; kk < 48; ++kk) {
                    const int k = q * 48 + kk;
                    const uint32_t wv = S->wrS[k * 49 + d];
                    m = fmaf(bflo(wv), S->sV0[k], m);
                    m = fmaf(bfhi(wv), S->sV1[k], m);
                }
                m += __shfl_xor(m, 1); m += __shfl_xor(m, 2);
                if (q == 0) S->sMv[d] = m;
            }
        }
        __syncthreads();                                         // B3

        // ---- gates -> hn(i); hn/kd message store ---------------------------
        {
            float hn = 0.f;
            if (t < DS) {
                float Mv = S->sMv[t];
                float r1 = sigm(S->sPre[t] + S->sGc[t]);
                float z1 = sigm(S->sPre[DS + t] + S->sGc[DS + t]);
                float n1 = tanhf_(S->sPre[2 * DS + t] + r1 * (S->sGc[2 * DS + t] + g2b));
                float Cv = (1.f - z1) * n1 + z1 * Mv;
                float r2 = sigm(S->sGc[3 * DS + t] + S->sPre[3 * DS + t]);
                float z2 = sigm(S->sGc[4 * DS + t] + S->sPre[4 * DS + t]);
                float n2 = tanhf_(S->sGc[5 * DS + t] + g5b + r2 * S->sPre[5 * DS + t]);
                hn = Cv + (1.f - z2) * n2 + z2 * S->sXv[t];
                S->sHn[t] = hn;
                hout[(size_t)row * G3 + dg0 + t] = hn;
                if (!ISL2) HcW[((size_t)row * NW + w) * DS + t] = packvs(hn, STH + i);
                agstore(myHS + t, packvs(hn, stamp));
            }
            if (wave == 0) {
                float v = hn * wkv;
                #pragma unroll
                for (int o = 32; o; o >>= 1) v += __shfl_xor(v, o);
                if (lane == 0) { S->sSaved[6] = v; agstore(myHS + 144, packvs(v, stamp)); }
            }
        }
        __syncthreads();                                         // B4

        // ---- PhF: E(i+1) (j<=i-1) + capture + Hw[i] pack -------------------
        const float xqn = ISL2 ? S->sSaved[3] : (S->sRedX[0] + S->sRedX[1] + S->sRedX[2]);
        if (t < N_) {
            if (t == i) { S->sSavedA[0] = S->sAdjN[t]; S->sSavedS[0] = S->sSmN[t]; }
            float e = 0.f;
            if (t < i && S->sAdjN[t] > 0.5f) e = __expf(xqn + S->sKsc[t]);
            float b0v = e * S->sSmN[t];
            S->sA0[t] = b0v; S->sA1[t] = e - b0v;
            float ps = e;
            #pragma unroll
            for (int o = 32; o; o >>= 1) ps += __shfl_xor(ps, o);
            if (lane == 0) S->sRedS[wave] = ps;
        } else if (t < N_ + KD) {
            const int kk2 = t - N_;
            Hw[(size_t)kk2 * N_ + i] = f2bf(S->sHn[2 * kk2]) | (f2bf(S->sHn[2 * kk2 + 1]) << 16);
        }
        __syncthreads();                                         // B5

        // ---- PhG: U(i+1) over j<=i-1; su message store ---------------------
        if (t < 384) {
            const int ilim = i;
            const int kd = t >> 4, jp = t & 15;
            const uint32_t* hp = Hw + (size_t)kd * N_;
            float u0l = 0.f, u0h = 0.f, u1l = 0.f, u1h = 0.f;
            int j = jp;
            while (j + 48 < ilim) {
                uint32_t h0 = hp[j], h1 = hp[j + 16], h2 = hp[j + 32], h3 = hp[j + 48];
                float b0, b1;
                b0 = S->sA0[j];      b1 = S->sA1[j];
                u0l = fmaf(b0, bflo(h0), u0l); u0h = fmaf(b0, bfhi(h0), u0h);
                u1l = fmaf(b1, bflo(h0), u1l); u1h = fmaf(b1, bfhi(h0), u1h);
                b0 = S->sA0[j + 16]; b1 = S->sA1[j + 16];
                u0l = fmaf(b0, bflo(h1), u0l); u0h = fmaf(b0, bfhi(h1), u0h);
                u1l = fmaf(b1, bflo(h1), u1l); u1h = fmaf(b1, bfhi(h1), u1h);
                b0 = S->sA0[j + 32]; b1 = S->sA1[j + 32];
                u0l = fmaf(b0, bflo(h2), u0l); u0h = fmaf(b0, bfhi(h2), u0h);
                u1l = fmaf(b1, bflo(h2), u1l); u1h = fmaf(b1, bfhi(h2), u1h);
                b0 = S->sA0[j + 48]; b1 = S->sA1[j + 48];
                u0l = fmaf(b0, bflo(h3), u0l); u0h = fmaf(b0, bfhi(h3), u0h);
                u1l = fmaf(b1, bflo(h3), u1l); u1h = fmaf(b1, bfhi(h3), u1h);
                j += 64;
            }
            for (; j < ilim; j += 16) {
                uint32_t hv = hp[j];
                float b0 = S->sA0[j], b1 = S->sA1[j];
                u0l = fmaf(b0, bflo(hv), u0l); u0h = fmaf(b0, bfhi(hv), u0h);
                u1l = fmaf(b1, bflo(hv), u1l); u1h = fmaf(b1, bfhi(hv), u1h);
            }
            #pragma unroll
            for (int o = 1; o <= 8; o <<= 1) {
                u0l += __shfl_xor(u0l, o); u0h += __shfl_xor(u0h, o);
                u1l += __shfl_xor(u1l, o); u1h += __shfl_xor(u1h, o);
            }
            if (jp == 0) {
                S->su0[2 * kd] = u0l; S->su0[2 * kd + 1] = u0h;
                S->su1[2 * kd] = u1l; S->su1[2 * kd + 1] = u1h;
                agstore(myHS + 48 + 2 * kd,     packvs(u0l, stamp));
                agstore(myHS + 48 + 2 * kd + 1, packvs(u0h, stamp));
                agstore(myHS + 96 + 2 * kd,     packvs(u1l, stamp));
                agstore(myHS + 96 + 2 * kd + 1, packvs(u1h, stamp));
            }
        }
        __syncthreads();                                         // B6
        xqc = xqn;
    }
}

// ---------------------------------------------------------------------------
// PRE worker — unchanged.
// ---------------------------------------------------------------------------
__device__ void worker_body(WorkSm* Wm, int b, int w, int t,
    const uint32_t* __restrict__ Wp4g, const float* __restrict__ bias2,
    const float* __restrict__ wq2,
    const u64* __restrict__ HcR, u64* __restrict__ PREcW, u64* __restrict__ XQcW)
{
    const int lane = t & 63, wave = t >> 6;
    const int c = t >> 1, kh = t & 1;
    uint4 wpreg[12];
    {
        const uint4* v4 = (const uint4*)Wp4g;
        #pragma unroll
        for (int p4 = 0; p4 < 12; ++p4) wpreg[p4] = v4[(12 * kh + p4) * GC + c];
    }
    float bv = 0.f;
    if (kh == 0) bv = bias2[192 * (c / DS) + w * DS + (c % DS)];
    float wqt = (t < DH_) ? wq2[t] : 0.f;
    for (int i = 0; i < N_; ++i) {
        if (t < DH_) {
            const u64* p = HcR + ((size_t)(b * N_ + i) * NW + (t / DS)) * DS + (t % DS);
            u64 v; do { v = agload(p); } while ((uint32_t)(v >> 32) != (uint32_t)(STH + i));
            Wm->sX[t] = __uint_as_float((uint32_t)v);
        }
        __syncthreads();
        {
            float g = 0.f;
            #pragma unroll
            for (int p4 = 0; p4 < 12; ++p4) {
                const uint4 wv = wpreg[p4];
                const int m0 = 8 * (12 * kh + p4);
                g = fmaf(Wm->sX[m0 + 0], bflo(wv.x), g); g = fmaf(Wm->sX[m0 + 1], bfhi(wv.x), g);
                g = fmaf(Wm->sX[m0 + 2], bflo(wv.y), g); g = fmaf(Wm->sX[m0 + 3], bfhi(wv.y), g);
                g = fmaf(Wm->sX[m0 + 4], bflo(wv.z), g); g = fmaf(Wm->sX[m0 + 5], bfhi(wv.z), g);
                g = fmaf(Wm->sX[m0 + 6], bflo(wv.w), g); g = fmaf(Wm->sX[m0 + 7], bfhi(wv.w), g);
            }
            g += __shfl_xor(g, 1);
            if (kh == 0) Wm->sPv[c] = g + bv;
        }
        if (w == 0) {
            float px = (t < DH_) ? Wm->sX[t] * wqt : 0.f;
            #pragma unroll
            for (int o = 32; o; o >>= 1) px += __shfl_xor(px, o);
            if (t < DH_ && lane == 0) Wm->sRed[wave] = px;
        }
        __syncthreads();
        if (t < 144) {
            u64 v = ((u64)(uint32_t)(STP + i) << 32)
                  | f2bf(Wm->sPv[2 * t]) | (f2bf(Wm->sPv[2 * t + 1]) << 16);
            agstore(&PREcW[((size_t)(b * N_ + i) * NW + w) * 144 + t], v);
        }
        if (w == 0 && t == 0)
            agstore(&XQcW[b * N_ + i],
                    packvs(Wm->sRed[0] + Wm->sRed[1] + Wm->sRed[2], STQ + i));
        __syncthreads();
    }
}

// ---------------------------------------------------------------------------
// Single fused kernel.
// ---------------------------------------------------------------------------
__global__ __launch_bounds__(576, 1) void pipeline_kernel(
    const float* __restrict__ features, const float* __restrict__ fc1_w,
    const float* __restrict__ fc1_b,
    const float* __restrict__ adj, const float* __restrict__ smask,
    const float* __restrict__ gatw,
    const float* __restrict__ wr0, const float* __restrict__ wr1,
    const float* __restrict__ c_wih, const float* __restrict__ c_whh,
    const float* __restrict__ c_bih, const float* __restrict__ c_bhh,
    const float* __restrict__ p_wih, const float* __restrict__ p_whh,
    const float* __restrict__ p_bih, const float* __restrict__ p_bhh,
    const float* __restrict__ mw0, const float* __restrict__ mb0,
    const float* __restrict__ mw1, const float* __restrict__ mb1,
    const float* __restrict__ mw2, const float* __restrict__ mb2,
    float* __restrict__ Hcat, float* __restrict__ PREg,
    float* __restrict__ WpreT, uint32_t* __restrict__ WfG,
    uint32_t* __restrict__ Wr4, uint32_t* __restrict__ Wp4w,
    float* __restrict__ biasPre, float* __restrict__ gbx,
    uint32_t* __restrict__ Hb, u64* __restrict__ HS,
    u64* __restrict__ Hc, u64* __restrict__ PREc, u64* __restrict__ XQc,
    u64* __restrict__ Fp, u64* __restrict__ Fd,
    float* __restrict__ out)
{
    __shared__ __align__(16) char smem[sizeof(SmemAll)];
    const int blk = blockIdx.x, t = threadIdx.x;
    const int wgid = blk;
    const int b = blk & 7, r12 = blk >> 3;
    const int role = r12 >> 2, w = r12 & 3;

    // ---- prepack (all WGs) -------------------------------------------------
    for (int j = 0; j < 4; ++j) {
        int idx = wgid * 576 + t + 55296 * j;
        prepack_slice(idx, wr0, wr1, c_wih, c_whh, c_bih, c_bhh,
                      p_wih, p_whh, p_bih, p_bhh,
                      WpreT, Wr4, Wp4w, biasPre, gbx);
    }
    wf_tile(wgid, t, wr0, wr1, c_whh, p_wih, WfG);
    flag_sync(Fp, wgid, t, SPK);

    // ---- fc1 + PRE-l1 prologue ---------------------------------------------
    prologue(smem, wgid, t, features, fc1_w, fc1_b, WpreT, biasPre,
             Hcat, PREg, Fp);

    // ---- roles -------------------------------------------------------------
    float* As = out + 393216;
    if (role == 0) {
        scan_body<0>((ScanSm*)smem, b, w, t,
            Hcat, Hcat + 192, PREg, adj, smask,
            WfG, Wr4, gbx, gatw,
            Hb + (size_t)(b * NW + w) * KD * N_, HS,
            Hc, nullptr, nullptr, nullptr,
            As + (size_t)b * (L_ * N_ * N_), 1);
        __threadfence();
        __syncthreads();
        if (t == 0) agstore(&Fd[b * 8 + w], packvs(0.f, SDN));
    } else if (role == 2) {
        scan_body<1>((ScanSm*)smem, b, w, t,
            nullptr, Hcat + 384, nullptr, adj, smask,
            WfG + (size_t)NW * 288 * 192, Wr4 + NW * 9216, gbx + 384, gatw + 384,
            Hb + (size_t)(32 + b * NW + w) * KD * N_, HS + HSR,
            nullptr, Hc, PREc, XQc,
            As + (size_t)b * (L_ * N_ * N_) + N_ * N_, 30001);
        __threadfence();
        __syncthreads();
        if (t == 0) agstore(&Fd[b * 8 + 4 + w], packvs(0.f, SDN));
    } else {
        worker_body((WorkSm*)smem, b, w, t,
            Wp4w + (size_t)w * 27648, biasPre + G6, gatw + 384,
            Hc, PREc, XQc);
    }

    // ---- MLP epilogue (all WGs) --------------------------------------------
    mlp_tail(smem, wgid, t, Hcat, mw0, mb0, mw1, mb1, mw2, mb2, out, Fd);
}

// ---------------------------------------------------------------------------
extern "C" void kernel_launch(void* const* d_in, const int* in_sizes, int n_in,
                              void* d_out, int out_size, void* d_ws, size_t ws_size,
                              hipStream_t stream)
{
    const float* features = (const float*)d_in[0];
    const float* adj      = (const float*)d_in[1];
    const float* smask    = (const float*)d_in[2];
    const float* fc1_w = (const float*)d_in[5];
    const float* fc1_b = (const float*)d_in[6];
    const float* gat_w = (const float*)d_in[7];
    const float* wr0   = (const float*)d_in[9];
    const float* wr1   = (const float*)d_in[10];
    const float* c_wih = (const float*)d_in[11];
    const float* c_whh = (const float*)d_in[12];
    const float* c_bih = (const float*)d_in[13];
    const float* c_bhh = (const float*)d_in[14];
    const float* p_wih = (const float*)d_in[15];
    const float* p_whh = (const float*)d_in[16];
    const float* p_bih = (const float*)d_in[17];
    const float* p_bhh = (const float*)d_in[18];
    const float* mw0 = (const float*)d_in[19];
    const float* mb0 = (const float*)d_in[20];
    const float* mw1 = (const float*)d_in[21];
    const float* mb1 = (const float*)d_in[22];
    const float* mw2 = (const float*)d_in[23];
    const float* mb2 = (const float*)d_in[24];
    float* out = (float*)d_out;

    char* wsb = (char*)d_ws;
    size_t off = 0;
    auto carve = [&](size_t bytes) -> char* {
        char* p = wsb + off;
        off = (off + bytes + 255) & ~(size_t)255;
        return p;
    };
    float* Hcat     = (float*)carve(2048ull * 576 * 4);
    float* PREg     = (float*)carve(2048ull * 1152 * 4);
    float* WpreT    = (float*)carve(192ull * 1152 * 4);
    uint32_t* WfG   = (uint32_t*)carve(2ull * NW * 288 * 192 * 4);   // fused Gc weights
    uint32_t* Wr4   = (uint32_t*)carve(2ull * NW * 9216 * 4);
    uint32_t* Wp4w  = (uint32_t*)carve((size_t)NW * 27648 * 4);
    float* biasPre  = (float*)carve(2ull * 1152 * 4);
    float* gbx      = (float*)carve(2ull * 384 * 4);
    uint32_t* Hb    = (uint32_t*)carve(64ull * KD * 256 * 4);
    u64* HS         = (u64*)carve(2ull * HSR * 8);                   // 2 roles
    u64* Hc         = (u64*)carve(8ull * 256 * NW * DS * 8);
    u64* PREc       = (u64*)carve(8ull * 256 * NW * 144 * 8);
    u64* XQc        = (u64*)carve(8ull * 256 * 8);
    u64* Fp         = (u64*)carve(288ull * 8);
    u64* Fd         = (u64*)carve(64ull * 8);

    pipeline_kernel<<<dim3(96), 576, 0, stream>>>(
        features, fc1_w, fc1_b, adj, smask, gat_w,
        wr0, wr1, c_wih, c_whh, c_bih, c_bhh, p_wih, p_whh, p_bih, p_bhh,
        mw0, mb0, mw1, mb1, mw2, mb2,
        Hcat, PREg, WpreT, WfG, Wr4, Wp4w, biasPre, gbx,
        Hb, HS, Hc, PREc, XQc, Fp, Fd, out);
}

// Round 5
// 3721.751 us; speedup vs baseline: 1.0576x; 1.0576x over previous
//
#include <hip/hip_runtime.h>
#include <stdint.h>

#define N_  256
#define DH_ 192
#define G3  576
#define G6  1152
#define STH 10001  // Hc channel stamp base
#define STP 20001  // PREc channel stamp base
#define SPK 50000  // prepack done
#define SF1 50001  // fc1 done
#define SF2 50002  // PRE-l1 done
#define SDN 60001  // scan done

typedef unsigned long long u64;

__device__ __forceinline__ float bflo(uint32_t u) { return __uint_as_float(u << 16); }
__device__ __forceinline__ float bfhi(uint32_t u) { return __uint_as_float(u & 0xffff0000u); }
__device__ __forceinline__ uint32_t f2bf(float f) {
    uint32_t x = __float_as_uint(f);
    x += 0x7fffu + ((x >> 16) & 1u);          // RNE
    return x >> 16;
}
__device__ __forceinline__ float sigm(float x)  { return 1.f / (1.f + __expf(-x)); }
__device__ __forceinline__ float tanhf_(float x){ return 1.f - 2.f / (1.f + __expf(2.f * x)); }
__device__ __forceinline__ u64 packvs(float v, int st) {
    return ((u64)(uint32_t)st << 32) | __float_as_uint(v);
}
__device__ __forceinline__ u64 agload(const u64* p) {
    return __hip_atomic_load(p, __ATOMIC_RELAXED, __HIP_MEMORY_SCOPE_AGENT);
}
__device__ __forceinline__ void agstore(u64* p, u64 v) {
    __hip_atomic_store(p, v, __ATOMIC_RELAXED, __HIP_MEMORY_SCOPE_AGENT);
}
__device__ __forceinline__ float u2f(u64 v) { return __uint_as_float((uint32_t)v); }

// ---------------------------------------------------------------------------
// LDS. Full-width scan: the whole per-(batch,layer) recurrence lives in ONE
// 576-thread WG -> no inter-WG exchange inside the step.  ~144.7 KB.
// ---------------------------------------------------------------------------
struct ScanSm {
    uint32_t Hw[N_ * 96];               // 98,304 B  history [j][kp] (bf16 pairs)
    float sPre[2][G6];                  // 9,216
    float sXv[2][DH_];                  // 1,536
    float sAdj[2][N_];                  // 2,048
    float sSm[2][N_];                   // 2,048
    float sKsc[N_];                     // 1,024
    float sA0[N_], sA1[N_];             // 2,048
    float sHn[DH_];                     // 768
    float sU0p[12][DH_], sU1p[12][DH_]; // 18,432
    float sMp[3][DH_];                  // 2,304
    float sM[DH_];                      // 768
    float su0[DH_], su1[DH_];           // 1,536
    float sGc[G6];                      // 4,608
    float sRedS[4], sRedK[4];           // 32
};
struct WorkSm { float sX[DH_]; };
struct PrologSm {
    float sA[8][768];
    float sRed[3][8][192];
};
struct MlpSm {
    float sH[8][576];
    float sRed[3][8][192];
    float sT[8][192];
};
union SmemAll { ScanSm s; WorkSm w; PrologSm p; MlpSm m; };

// ---------------------------------------------------------------------------
// Prepack (idx in [0, 221184), each exactly once):
//  WpreT  : PRE-l1 weights (as before)
//  Wc     : [l][k4][cp] uint4-friendly bf16 col-pairs of Wcomb=[cwhh;pwih]
//  Wp     : same layout for worker (layer-1 [cwih;pwhh])
//  biasPre, gbx : folded biases (as before)
// ---------------------------------------------------------------------------
__device__ void prepack_slice(int idx,
    const float* __restrict__ c_wih, const float* __restrict__ c_whh,
    const float* __restrict__ c_bih, const float* __restrict__ c_bhh,
    const float* __restrict__ p_wih, const float* __restrict__ p_whh,
    const float* __restrict__ p_bih, const float* __restrict__ p_bhh,
    float* __restrict__ WpreT, uint32_t* __restrict__ Wc,
    uint32_t* __restrict__ Wp, float* __restrict__ biasPre,
    float* __restrict__ gbx)
{
    {   // WpreT (layer-0 PRE weights, k-major rows of [cwih0; pwhh0])
        int k = idx / G6, r = idx - k * G6;
        float w = (r < G3) ? c_wih[r * DH_ + k] : p_whh[(r - G3) * DH_ + k];
        WpreT[k * G6 + r] = w;
    }
    {   // Wc: u32 at ((l*48+k4)*576+cp)*4+kk == idx
        int l = idx / 110592, o = idx - l * 110592;
        int k4 = o / 2304, r3 = o - k4 * 2304, cp = r3 >> 2, kk = r3 & 3;
        int k = 4 * k4 + kk, c0 = 2 * cp;
        const float* W = (c0 < G3) ? (c_whh + (size_t)(l * G3 + c0) * DH_)
                                   : (p_wih + (size_t)(l * G3 + c0 - G3) * DH_);
        Wc[idx] = f2bf(W[k]) | (f2bf(W[DH_ + k]) << 16);
    }
    if (idx < 110592) {   // Wp: layer-1 [cwih; pwhh]
        int k4 = idx / 2304, r3 = idx - k4 * 2304, cp = r3 >> 2, kk = r3 & 3;
        int k = 4 * k4 + kk, c0 = 2 * cp;
        const float* W = (c0 < G3) ? (c_wih + (size_t)(G3 + c0) * DH_)
                                   : (p_whh + (size_t)(G3 + c0 - G3) * DH_);
        Wp[idx] = f2bf(W[k]) | (f2bf(W[DH_ + k]) << 16);
    }
    if (idx < 2304) {
        int l = idx / G6, c = idx - l * G6;
        float base = (c < G3) ? c_bih[l * G3 + c] : p_bhh[l * G3 + c - G3];
        float fold = 0.f;
        if (c < 384)                   fold = c_bhh[l * G3 + c];
        else if (c >= G3 && c < 960)   fold = p_bih[l * G3 + c - G3];
        biasPre[idx] = base + fold;
    }
    if (idx < 768) {
        int l = idx / 384, c = idx - l * 384;
        gbx[idx] = (c < DH_) ? c_bhh[l * G3 + 384 + c]
                             : p_bih[l * G3 + 384 + (c - DH_)];
    }
}

// ---------------------------------------------------------------------------
// Global sync among the 96 co-resident WGs via stamped flags.
// ---------------------------------------------------------------------------
__device__ void flag_sync(u64* flags, int wgid, int t, int stamp)
{
    __threadfence();
    __syncthreads();
    if (t == 0) agstore(&flags[wgid], packvs(0.f, stamp));
    if (t < 96) {
        while ((uint32_t)(agload(&flags[t]) >> 32) != (uint32_t)stamp) {}
    }
    __syncthreads();
    __threadfence();
    __syncthreads();
}

// ---------------------------------------------------------------------------
// Prologue: fc1 (H0 = relu(features@fc1_w+b)) then PRE-l1 = H0@WpreT+biasPre.
// All 96 WGs participate. Unchanged from verified rounds.
// ---------------------------------------------------------------------------
__device__ void prologue(char* smem, int wgid, int t,
    const float* __restrict__ features, const float* __restrict__ fc1_w,
    const float* __restrict__ fc1_b, const float* __restrict__ WpreT,
    const float* __restrict__ biasPre,
    float* __restrict__ Hcat, float* __restrict__ PREg, u64* __restrict__ Fp)
{
    PrologSm* P = (PrologSm*)smem;
    const int c = t % 192, kg = t / 192;
    for (int tt = wgid; tt < 256; tt += 96) {
        const int r0 = tt * 8;
        for (int q = t; q < 1536; q += 576) {
            int r = q / 192, c4 = q % 192;
            *(float4*)&P->sA[r][4 * c4] = *(const float4*)(features + (size_t)(r0 + r) * 768 + 4 * c4);
        }
        __syncthreads();
        {
            const float* bp = fc1_w + (size_t)(kg * 256) * 192 + c;
            float acc[8] = {0.f, 0.f, 0.f, 0.f, 0.f, 0.f, 0.f, 0.f};
            #pragma unroll 8
            for (int kk = 0; kk < 256; ++kk) {
                float bv = bp[(size_t)kk * 192];
                #pragma unroll
                for (int rr = 0; rr < 8; ++rr) acc[rr] += P->sA[rr][kg * 256 + kk] * bv;
            }
            #pragma unroll
            for (int rr = 0; rr < 8; ++rr) P->sRed[kg][rr][c] = acc[rr];
        }
        __syncthreads();
        if (t < 192) {
            float bv = fc1_b[t];
            #pragma unroll
            for (int rr = 0; rr < 8; ++rr) {
                float v = P->sRed[0][rr][t] + P->sRed[1][rr][t] + P->sRed[2][rr][t] + bv;
                Hcat[(size_t)(r0 + rr) * G3 + t] = fmaxf(v, 0.f);
            }
        }
        __syncthreads();
    }
    flag_sync(Fp + 96, wgid, t, SF1);
    {
        const float bpa = biasPre[t], bpb = biasPre[576 + t];
        for (int tt = wgid; tt < 256; tt += 96) {
            const int r0 = tt * 8;
            for (int q = t; q < 384; q += 576) {
                int r = q / 48, c4 = q % 48;
                *(float4*)&P->sA[r][4 * c4] = *(const float4*)(Hcat + (size_t)(r0 + r) * G3 + 4 * c4);
            }
            __syncthreads();
            {
                const float* b0 = WpreT + t;
                float a0[8] = {0.f,0.f,0.f,0.f,0.f,0.f,0.f,0.f};
                float a1[8] = {0.f,0.f,0.f,0.f,0.f,0.f,0.f,0.f};
                #pragma unroll 4
                for (int k = 0; k < 192; ++k) {
                    float bva = b0[(size_t)k * G6];
                    float bvb = b0[(size_t)k * G6 + 576];
                    #pragma unroll
                    for (int rr = 0; rr < 8; ++rr) {
                        float av = P->sA[rr][k];
                        a0[rr] += av * bva; a1[rr] += av * bvb;
                    }
                }
                #pragma unroll
                for (int rr = 0; rr < 8; ++rr) {
                    PREg[(size_t)(r0 + rr) * G6 + t]       = a0[rr] + bpa;
                    PREg[(size_t)(r0 + rr) * G6 + 576 + t] = a1[rr] + bpb;
                }
            }
            __syncthreads();
        }
    }
    flag_sync(Fp + 192, wgid, t, SF2);
}

// ---------------------------------------------------------------------------
// Epilogue: 3-layer MLP head on concat(H0|H1|H2). Waits on 16 scan-done flags.
// ---------------------------------------------------------------------------
__device__ void mlp_tail(char* smem, int wgid, int t,
    const float* __restrict__ Hcat,
    const float* __restrict__ mw0, const float* __restrict__ mb0,
    const float* __restrict__ mw1, const float* __restrict__ mb1,
    const float* __restrict__ mw2, const float* __restrict__ mb2,
    float* __restrict__ out, u64* __restrict__ Fd)
{
    if (t < 16) {
        while ((uint32_t)(agload(&Fd[t]) >> 32) != (uint32_t)SDN)
            __builtin_amdgcn_s_sleep(2);
    }
    __syncthreads();
    __threadfence();
    __syncthreads();
    MlpSm* M = (MlpSm*)smem;
    const int c = t % 192, kg = t / 192;
    for (int tt = wgid; tt < 256; tt += 96) {
        const int r0 = tt * 8;
        for (int q = t; q < 1152; q += 576) {
            int r = q / 144, c4 = q % 144;
            *(float4*)&M->sH[r][4 * c4] = *(const float4*)(Hcat + (size_t)(r0 + r) * G3 + 4 * c4);
        }
        __syncthreads();
        {
            const float* bp = mw0 + (size_t)(kg * 192) * 192 + c;
            float acc[8] = {0.f,0.f,0.f,0.f,0.f,0.f,0.f,0.f};
            #pragma unroll 8
            for (int kk = 0; kk < 192; ++kk) {
                float bv = bp[(size_t)kk * 192];
                #pragma unroll
                for (int rr = 0; rr < 8; ++rr) acc[rr] += M->sH[rr][kg * 192 + kk] * bv;
            }
            #pragma unroll
            for (int rr = 0; rr < 8; ++rr) M->sRed[kg][rr][c] = acc[rr];
        }
        __syncthreads();
        if (t < 192) {
            float bv = mb0[t];
            #pragma unroll
            for (int rr = 0; rr < 8; ++rr)
                M->sT[rr][t] = fmaxf(M->sRed[0][rr][t] + M->sRed[1][rr][t] + M->sRed[2][rr][t] + bv, 0.f);
        }
        __syncthreads();
        {
            const float* bp = mw1 + (size_t)(kg * 64) * 192 + c;
            float acc[8] = {0.f,0.f,0.f,0.f,0.f,0.f,0.f,0.f};
            #pragma unroll 8
            for (int kk = 0; kk < 64; ++kk) {
                float bv = bp[(size_t)kk * 192];
                #pragma unroll
                for (int rr = 0; rr < 8; ++rr) acc[rr] += M->sT[rr][kg * 64 + kk] * bv;
            }
            #pragma unroll
            for (int rr = 0; rr < 8; ++rr) M->sRed[kg][rr][c] = acc[rr];
        }
        __syncthreads();
        if (t < 192) {
            float bv = mb1[t];
            #pragma unroll
            for (int rr = 0; rr < 8; ++rr)
                M->sH[rr][t] = fmaxf(M->sRed[0][rr][t] + M->sRed[1][rr][t] + M->sRed[2][rr][t] + bv, 0.f);
        }
        __syncthreads();
        {
            const float* bp = mw2 + (size_t)(kg * 64) * 192 + c;
            float acc[8] = {0.f,0.f,0.f,0.f,0.f,0.f,0.f,0.f};
            #pragma unroll 8
            for (int kk = 0; kk < 64; ++kk) {
                float bv = bp[(size_t)kk * 192];
                #pragma unroll
                for (int rr = 0; rr < 8; ++rr) acc[rr] += M->sH[rr][kg * 64 + kk] * bv;
            }
            #pragma unroll
            for (int rr = 0; rr < 8; ++rr) M->sRed[kg][rr][c] = acc[rr];
        }
        __syncthreads();
        if (t < 192) {
            float bv = mb2[t];
            #pragma unroll
            for (int rr = 0; rr < 8; ++rr)
                out[(size_t)(r0 + rr) * 192 + t] =
                    M->sRed[0][rr][t] + M->sRed[1][rr][t] + M->sRed[2][rr][t] + bv;
        }
        __syncthreads();
    }
}

// ---------------------------------------------------------------------------
// Full-width scan: one WG per (batch, layer). No per-step inter-WG waits:
// kdot, softmax, U-matvec, M, Gc, gates are all intra-WG.  L2 consumes L1's
// rows via stamped channels (acyclic pipeline -> constant lag, no deadlock).
// NOTE: the per-query additive constants xq_i and gat_b cancel in softmax
// (common to all j), so they are omitted entirely.
// ---------------------------------------------------------------------------
template<int ISL2>
__device__ void scan_full(ScanSm* S, int b, int t,
    const float* __restrict__ xin, float* __restrict__ hout,
    const float* __restrict__ PREg,
    const float* __restrict__ adj, const float* __restrict__ smask,
    const uint32_t* __restrict__ Wc,                  // layer base (u32*)
    const float* __restrict__ wr0l, const float* __restrict__ wr1l,
    const float* __restrict__ gbxl, const float* __restrict__ wkp,
    u64* __restrict__ HcW, const u64* __restrict__ HcR,
    const u64* __restrict__ PREcR,
    float* __restrict__ AsB)
{
    const int lane = t & 63, wave = t >> 6;
    const float* adjB = adj   + (size_t)b * N_ * N_;
    const float* smB  = smask + (size_t)b * N_ * N_;
    const int dM = t % DH_, kgM = t / DH_;     // Ph3 mapping (M matvec)
    const int kpU = t % 48,  jgU = t / 48;     // Ph2 mapping (U matvec)

    // wr -> registers: packed (wr0,wr1) bf16 pair for (dM, kgM*64+kk)
    uint32_t wreg[64];
    for (int kk = 0; kk < 64; ++kk) {
        int k = kgM * 64 + kk;
        wreg[kk] = f2bf(wr0l[dM * DH_ + k]) | (f2bf(wr1l[dM * DH_ + k]) << 16);
    }
    float wkv = 0.f, g2b = 0.f, g5b = 0.f;
    if (t < DH_) { wkv = wkp[t]; g2b = gbxl[t]; g5b = gbxl[DH_ + t]; }
    if (t < N_) AsB[t] = 0.f;                  // As row 0

    // ---- init: row 0 -> buf[0], row 1 -> buf[1] ----------------------------
    if (!ISL2) {
        for (int q = t; q < 800; q += 576) {
            if (q < 288)      *(float4*)&S->sPre[0][4*q] = *(const float4*)(PREg + (size_t)(b*N_)*G6 + 4*q);
            else if (q < 336) { int q2=q-288; *(float4*)&S->sXv[0][4*q2] = *(const float4*)(xin + (size_t)(b*N_)*G3 + 4*q2); }
            else if (q < 624) { int q2=q-336; *(float4*)&S->sPre[1][4*q2] = *(const float4*)(PREg + (size_t)(b*N_+1)*G6 + 4*q2); }
            else if (q < 672) { int q2=q-624; *(float4*)&S->sXv[1][4*q2] = *(const float4*)(xin + (size_t)(b*N_+1)*G3 + 4*q2); }
            else if (q < 736) { int q2=q-672; *(float4*)&S->sAdj[1][4*q2] = *(const float4*)(adjB + N_ + 4*q2); }
            else              { int q2=q-736; *(float4*)&S->sSm[1][4*q2] = *(const float4*)(smB + N_ + 4*q2); }
        }
    } else {
        for (int q = t; q < 1664; q += 576) {
            if (q < 192) {
                const u64* p = HcR + (size_t)(b*N_)*DH_ + q;
                u64 v; do { v = agload(p); } while ((uint32_t)(v >> 32) != (uint32_t)STH);
                S->sXv[0][q] = u2f(v);
            } else if (q < 768) {
                int idx = q - 192;
                const u64* p = PREcR + (size_t)(b*N_)*G3 + idx;
                u64 v; do { v = agload(p); } while ((uint32_t)(v >> 32) != (uint32_t)STP);
                uint32_t pl = (uint32_t)v;
                S->sPre[0][2*idx] = bflo(pl); S->sPre[0][2*idx+1] = bfhi(pl);
            } else if (q < 960) {
                int d = q - 768;
                const u64* p = HcR + (size_t)(b*N_+1)*DH_ + d;
                u64 v; do { v = agload(p); } while ((uint32_t)(v >> 32) != (uint32_t)(STH+1));
                S->sXv[1][d] = u2f(v);
            } else if (q < 1536) {
                int idx = q - 960;
                const u64* p = PREcR + (size_t)(b*N_+1)*G3 + idx;
                u64 v; do { v = agload(p); } while ((uint32_t)(v >> 32) != (uint32_t)(STP+1));
                uint32_t pl = (uint32_t)v;
                S->sPre[1][2*idx] = bflo(pl); S->sPre[1][2*idx+1] = bfhi(pl);
            } else if (q < 1600) { int q2 = q-1536; *(float4*)&S->sAdj[1][4*q2] = *(const float4*)(adjB + N_ + 4*q2); }
            else                 { int q2 = q-1600; *(float4*)&S->sSm[1][4*q2]  = *(const float4*)(smB  + N_ + 4*q2); }
        }
    }
    __syncthreads();

    // ---- step 0 gates (M = 0, Gc = 0) --------------------------------------
    if (t < DH_) {
        const float* Pr = S->sPre[0];
        float xv = S->sXv[0][t];
        float r1 = sigm(Pr[t]), z1 = sigm(Pr[DH_ + t]);
        float n1 = tanhf_(Pr[2*DH_ + t] + r1 * g2b);
        float Cv = (1.f - z1) * n1;
        float r2 = sigm(Pr[3*DH_ + t]), z2 = sigm(Pr[4*DH_ + t]);
        float n2 = tanhf_(g5b + r2 * Pr[5*DH_ + t]);
        float hn = Cv + (1.f - z2) * n2 + z2 * xv;
        S->sHn[t] = hn;
        hout[(size_t)(b*N_)*G3 + t] = hn;
        if (!ISL2) agstore(&HcW[(size_t)(b*N_)*DH_ + t], packvs(hn, STH));
        float px = hn * wkv;
        #pragma unroll
        for (int o = 32; o; o >>= 1) px += __shfl_xor(px, o);
        if (lane == 0) S->sRedK[wave] = px;
    }
    __syncthreads();

    for (int i = 1; i < N_; ++i) {
        const int row = b*N_ + i;
        const int pp = i & 1, pn = pp ^ 1;
        const int inx = (i + 1 < N_) ? i + 1 : N_ - 1;

        // ---- Ph1: softmax weights (t<256) || pack Hw[i-1] + prefetch -------
        if (t < N_) {
            float ksc;
            if (t == i - 1) { ksc = S->sRedK[0] + S->sRedK[1] + S->sRedK[2]; S->sKsc[i-1] = ksc; }
            else            ksc = S->sKsc[t];
            float e = (t < i && S->sAdj[pp][t] > 0.5f) ? __expf(ksc) : 0.f;
            float a0 = e * S->sSm[pp][t];
            S->sA0[t] = a0; S->sA1[t] = e - a0;
            float ps = e;
            #pragma unroll
            for (int o = 32; o; o >>= 1) ps += __shfl_xor(ps, o);
            if (lane == 0) S->sRedS[wave] = ps;
        } else {
            if (!ISL2) {
                for (int q = t - 256; q < 560; q += 320) {
                    if (q < 96) S->Hw[(i-1)*96 + q] = f2bf(S->sHn[2*q]) | (f2bf(S->sHn[2*q+1]) << 16);
                    else {
                        int j = q - 96;
                        if (j < 64)       *(float4*)&S->sAdj[pn][4*j] = *(const float4*)(adjB + (size_t)inx*N_ + 4*j);
                        else if (j < 128) { int j2=j-64;  *(float4*)&S->sSm[pn][4*j2]  = *(const float4*)(smB  + (size_t)inx*N_ + 4*j2); }
                        else if (j < 176) { int j2=j-128; *(float4*)&S->sXv[pn][4*j2]  = *(const float4*)(xin  + (size_t)(b*N_+inx)*G3 + 4*j2); }
                        else              { int j2=j-176; *(float4*)&S->sPre[pn][4*j2] = *(const float4*)(PREg + (size_t)(b*N_+inx)*G6 + 4*j2); }
                    }
                }
            } else {
                for (int q = t - 256; q < 992; q += 320) {
                    if (q < 96) S->Hw[(i-1)*96 + q] = f2bf(S->sHn[2*q]) | (f2bf(S->sHn[2*q+1]) << 16);
                    else if (q < 160) { int j = q-96;  *(float4*)&S->sAdj[pn][4*j] = *(const float4*)(adjB + (size_t)inx*N_ + 4*j); }
                    else if (q < 224) { int j = q-160; *(float4*)&S->sSm[pn][4*j]  = *(const float4*)(smB  + (size_t)inx*N_ + 4*j); }
                    else if (q < 416) {
                        int d = q - 224;
                        const u64* p = HcR + (size_t)(b*N_+inx)*DH_ + d;
                        u64 v; do { v = agload(p); } while ((uint32_t)(v >> 32) != (uint32_t)(STH+inx));
                        S->sXv[pn][d] = u2f(v);
                    } else {
                        int idx = q - 416;
                        const u64* p = PREcR + (size_t)(b*N_+inx)*G3 + idx;
                        u64 v; do { v = agload(p); } while ((uint32_t)(v >> 32) != (uint32_t)(STP+inx));
                        uint32_t pl = (uint32_t)v;
                        S->sPre[pn][2*idx] = bflo(pl); S->sPre[pn][2*idx+1] = bfhi(pl);
                    }
                }
            }
        }
        __syncthreads();                                         // B1

        // ---- Ph2: U-history partials (48 kp x 12 jg) -----------------------
        {
            float4 u0 = {0.f,0.f,0.f,0.f}, u1 = {0.f,0.f,0.f,0.f};
            const int kb = 2 * kpU;
            for (int j = jgU; j < i; j += 12) {
                uint32_t h0 = S->Hw[j*96 + kb], h1 = S->Hw[j*96 + kb + 1];
                float a0 = S->sA0[j], a1 = S->sA1[j];
                u0.x += a0*bflo(h0); u0.y += a0*bfhi(h0);
                u0.z += a0*bflo(h1); u0.w += a0*bfhi(h1);
                u1.x += a1*bflo(h0); u1.y += a1*bfhi(h0);
                u1.z += a1*bflo(h1); u1.w += a1*bfhi(h1);
            }
            *(float4*)&S->sU0p[jgU][4*kpU] = u0;
            *(float4*)&S->sU1p[jgU][4*kpU] = u1;
        }
        __syncthreads();                                         // B2

        // ---- Ph2b: reduce U -> su (invS-scaled) || write As row i ----------
        {
            float invS = 1.f / (S->sRedS[0] + S->sRedS[1] + S->sRedS[2] + S->sRedS[3]);
            if (t < DH_) {
                float v0 = 0.f, v1 = 0.f;
                #pragma unroll
                for (int g = 0; g < 12; ++g) { v0 += S->sU0p[g][t]; v1 += S->sU1p[g][t]; }
                S->su0[t] = v0 * invS; S->su1[t] = v1 * invS;
            } else if (t < DH_ + N_) {
                int j = t - DH_;
                AsB[(size_t)i*N_ + j] = (j < i) ? (S->sA0[j] + S->sA1[j]) * invS : 0.f;
            }
        }
        __syncthreads();                                         // B3

        // ---- Ph3: M partials (192 d x 3 kg) from register wr ---------------
        {
            float m = 0.f;
            const float4* s0 = (const float4*)&S->su0[kgM * 64];
            const float4* s1 = (const float4*)&S->su1[kgM * 64];
            #pragma unroll
            for (int k4 = 0; k4 < 16; ++k4) {
                float4 a = s0[k4], c = s1[k4];
                m += bflo(wreg[4*k4+0])*a.x + bfhi(wreg[4*k4+0])*c.x;
                m += bflo(wreg[4*k4+1])*a.y + bfhi(wreg[4*k4+1])*c.y;
                m += bflo(wreg[4*k4+2])*a.z + bfhi(wreg[4*k4+2])*c.z;
                m += bflo(wreg[4*k4+3])*a.w + bfhi(wreg[4*k4+3])*c.w;
            }
            S->sMp[kgM][dM] = m;
        }
        __syncthreads();                                         // B4
        if (t < DH_) S->sM[t] = S->sMp[0][t] + S->sMp[1][t] + S->sMp[2][t];
        __syncthreads();                                         // B5

        // ---- Ph4: Gc = Wcomb . M (cols 2t, 2t+1), Wc streamed from L2 ------
        {
            float g0 = 0.f, g1 = 0.f;
            const uint4* wp4 = (const uint4*)Wc;
            #pragma unroll 4
            for (int k4 = 0; k4 < 48; ++k4) {
                uint4 wv = wp4[k4*576 + t];
                float4 mv = *(const float4*)&S->sM[4*k4];
                g0 += bflo(wv.x)*mv.x + bflo(wv.y)*mv.y + bflo(wv.z)*mv.z + bflo(wv.w)*mv.w;
                g1 += bfhi(wv.x)*mv.x + bfhi(wv.y)*mv.y + bfhi(wv.z)*mv.z + bfhi(wv.w)*mv.w;
            }
            S->sGc[2*t] = g0; S->sGc[2*t+1] = g1;
        }
        __syncthreads();                                         // B6

        // ---- Ph5: gates -> hn(i); Hc store; kdot partials ------------------
        if (t < DH_) {
            const float* Pr = S->sPre[pp];
            const float* Gc = S->sGc;
            float Mv = S->sM[t];
            float r1 = sigm(Pr[t] + Gc[t]);
            float z1 = sigm(Pr[DH_+t] + Gc[DH_+t]);
            float n1 = tanhf_(Pr[2*DH_+t] + r1 * (Gc[2*DH_+t] + g2b));
            float Cv = (1.f - z1) * n1 + z1 * Mv;
            float r2 = sigm(Gc[3*DH_+t] + Pr[3*DH_+t]);
            float z2 = sigm(Gc[4*DH_+t] + Pr[4*DH_+t]);
            float n2 = tanhf_(Gc[5*DH_+t] + g5b + r2 * Pr[5*DH_+t]);
            float hn = Cv + (1.f - z2) * n2 + z2 * S->sXv[pp][t];
            S->sHn[t] = hn;
            hout[(size_t)row*G3 + t] = hn;
            if (!ISL2) agstore(&HcW[(size_t)row*DH_ + t], packvs(hn, STH + i));
            float px = hn * wkv;
            #pragma unroll
            for (int o = 32; o; o >>= 1) px += __shfl_xor(px, o);
            if (lane == 0) S->sRedK[wave] = px;
        }
        __syncthreads();                                         // B7
    }
}

// ---------------------------------------------------------------------------
// PRE-l2 worker: one WG per batch, full-width. Polls L1's hn row, streams Wp
// from L2, writes stamped PREc row (bias folded, bf16-pair packed).
// ---------------------------------------------------------------------------
__device__ void worker_full(float* sX, int b, int t,
    const uint32_t* __restrict__ Wp, const float* __restrict__ bias2,
    const u64* __restrict__ HcR, u64* __restrict__ PREcW)
{
    const float bv0 = bias2[2*t], bv1 = bias2[2*t + 1];
    const uint4* wp4 = (const uint4*)Wp;
    for (int i = 0; i < N_; ++i) {
        if (t < DH_) {
            const u64* p = HcR + (size_t)(b*N_ + i)*DH_ + t;
            u64 v; do { v = agload(p); } while ((uint32_t)(v >> 32) != (uint32_t)(STH + i));
            sX[t] = u2f(v);
        }
        __syncthreads();
        float g0 = 0.f, g1 = 0.f;
        #pragma unroll 4
        for (int k4 = 0; k4 < 48; ++k4) {
            uint4 wv = wp4[k4*576 + t];
            float4 xv = *(const float4*)&sX[4*k4];
            g0 += bflo(wv.x)*xv.x + bflo(wv.y)*xv.y + bflo(wv.z)*xv.z + bflo(wv.w)*xv.w;
            g1 += bfhi(wv.x)*xv.x + bfhi(wv.y)*xv.y + bfhi(wv.z)*xv.z + bfhi(wv.w)*xv.w;
        }
        u64 ov = ((u64)(uint32_t)(STP + i) << 32)
               | (u64)(f2bf(g0 + bv0) | (f2bf(g1 + bv1) << 16));
        agstore(&PREcW[(size_t)(b*N_ + i)*G3 + t], ov);
        __syncthreads();
    }
}

// ---------------------------------------------------------------------------
// Single fused kernel.
// ---------------------------------------------------------------------------
__global__ __launch_bounds__(576, 1) void pipeline_kernel(
    const float* __restrict__ features, const float* __restrict__ fc1_w,
    const float* __restrict__ fc1_b,
    const float* __restrict__ adj, const float* __restrict__ smask,
    const float* __restrict__ gatw,
    const float* __restrict__ wr0, const float* __restrict__ wr1,
    const float* __restrict__ c_wih, const float* __restrict__ c_whh,
    const float* __restrict__ c_bih, const float* __restrict__ c_bhh,
    const float* __restrict__ p_wih, const float* __restrict__ p_whh,
    const float* __restrict__ p_bih, const float* __restrict__ p_bhh,
    const float* __restrict__ mw0, const float* __restrict__ mb0,
    const float* __restrict__ mw1, const float* __restrict__ mb1,
    const float* __restrict__ mw2, const float* __restrict__ mb2,
    float* __restrict__ Hcat, float* __restrict__ PREg,
    float* __restrict__ WpreT, uint32_t* __restrict__ Wc,
    uint32_t* __restrict__ Wp,
    float* __restrict__ biasPre, float* __restrict__ gbx,
    u64* __restrict__ Hc, u64* __restrict__ PREc,
    u64* __restrict__ Fp, u64* __restrict__ Fd,
    float* __restrict__ out)
{
    __shared__ __align__(16) char smem[sizeof(SmemAll)];
    const int blk = blockIdx.x, t = threadIdx.x;

    // ---- prepack (all 96 WGs) ----------------------------------------------
    for (int j = 0; j < 4; ++j) {
        int idx = blk * 576 + t + 55296 * j;
        prepack_slice(idx, c_wih, c_whh, c_bih, c_bhh,
                      p_wih, p_whh, p_bih, p_bhh,
                      WpreT, Wc, Wp, biasPre, gbx);
    }
    flag_sync(Fp, blk, t, SPK);

    // ---- fc1 + PRE-l1 prologue (all 96 WGs) --------------------------------
    prologue(smem, blk, t, features, fc1_w, fc1_b, WpreT, biasPre,
             Hcat, PREg, Fp);

    // ---- roles -------------------------------------------------------------
    float* As = out + 393216;
    if (blk < 8) {
        const int b = blk;
        scan_full<0>((ScanSm*)smem, b, t,
            Hcat, Hcat + DH_, PREg, adj, smask,
            Wc, wr0, wr1, gbx, gatw + DH_,
            Hc, nullptr, nullptr,
            As + (size_t)b * (2 * N_ * N_));
        __threadfence();
        __syncthreads();
        if (t == 0) agstore(&Fd[b], packvs(0.f, SDN));
    } else if (blk < 16) {
        const int b = blk - 8;
        worker_full((float*)smem, b, t, Wp, biasPre + G6, Hc, PREc);
    } else if (blk < 24) {
        const int b = blk - 16;
        scan_full<1>((ScanSm*)smem, b, t,
            nullptr, Hcat + 2 * DH_, nullptr, adj, smask,
            Wc + 110592, wr0 + DH_ * DH_, wr1 + DH_ * DH_,
            gbx + 384, gatw + 384 + DH_,
            nullptr, Hc, PREc,
            As + (size_t)b * (2 * N_ * N_) + N_ * N_);
        __threadfence();
        __syncthreads();
        if (t == 0) agstore(&Fd[8 + b], packvs(0.f, SDN));
    }

    // ---- MLP epilogue (all 96 WGs) -----------------------------------------
    mlp_tail(smem, blk, t, Hcat, mw0, mb0, mw1, mb1, mw2, mb2, out, Fd);
}

// ---------------------------------------------------------------------------
extern "C" void kernel_launch(void* const* d_in, const int* in_sizes, int n_in,
                              void* d_out, int out_size, void* d_ws, size_t ws_size,
                              hipStream_t stream)
{
    const float* features = (const float*)d_in[0];
    const float* adj      = (const float*)d_in[1];
    const float* smask    = (const float*)d_in[2];
    const float* fc1_w = (const float*)d_in[5];
    const float* fc1_b = (const float*)d_in[6];
    const float* gat_w = (const float*)d_in[7];
    const float* wr0   = (const float*)d_in[9];
    const float* wr1   = (const float*)d_in[10];
    const float* c_wih = (const float*)d_in[11];
    const float* c_whh = (const float*)d_in[12];
    const float* c_bih = (const float*)d_in[13];
    const float* c_bhh = (const float*)d_in[14];
    const float* p_wih = (const float*)d_in[15];
    const float* p_whh = (const float*)d_in[16];
    const float* p_bih = (const float*)d_in[17];
    const float* p_bhh = (const float*)d_in[18];
    const float* mw0 = (const float*)d_in[19];
    const float* mb0 = (const float*)d_in[20];
    const float* mw1 = (const float*)d_in[21];
    const float* mb1 = (const float*)d_in[22];
    const float* mw2 = (const float*)d_in[23];
    const float* mb2 = (const float*)d_in[24];
    float* out = (float*)d_out;

    char* wsb = (char*)d_ws;
    size_t off = 0;
    auto carve = [&](size_t bytes) -> char* {
        char* p = wsb + off;
        off = (off + bytes + 255) & ~(size_t)255;
        return p;
    };
    float* Hcat     = (float*)carve(2048ull * 576 * 4);
    float* PREg     = (float*)carve(2048ull * 1152 * 4);
    float* WpreT    = (float*)carve(221184ull * 4);
    uint32_t* Wc    = (uint32_t*)carve(221184ull * 4);
    uint32_t* Wp    = (uint32_t*)carve(110592ull * 4);
    float* biasPre  = (float*)carve(2304ull * 4);
    float* gbx      = (float*)carve(768ull * 4);
    u64* Hc         = (u64*)carve(2048ull * 192 * 8);
    u64* PREc       = (u64*)carve(2048ull * 576 * 8);
    u64* Fp         = (u64*)carve(288ull * 8);
    u64* Fd         = (u64*)carve(64ull * 8);

    pipeline_kernel<<<dim3(96), 576, 0, stream>>>(
        features, fc1_w, fc1_b, adj, smask, gat_w,
        wr0, wr1, c_wih, c_whh, c_bih, c_bhh, p_wih, p_whh, p_bih, p_bhh,
        mw0, mb0, mw1, mb1, mw2, mb2,
        Hcat, PREg, WpreT, Wc, Wp, biasPre, gbx,
        Hc, PREc, Fp, Fd, out);
}

// Round 6
// 2363.706 us; speedup vs baseline: 1.6653x; 1.5745x over previous
//
#include <hip/hip_runtime.h>
#include <stdint.h>

#define B_  8
#define N_  256
#define DH_ 192
#define L_  2
#define G3  576
#define G6  1152
#define NW  4      // WGs per batch per role
#define DS  48     // d-slice per WG
#define KD  24     // H-history dwords per WG (48 bf16)
#define GC  288    // g-cols per WG
#define MSGR (2 * 8 * NW * 576)   // floats per role (2 parities x 8 b x 4 w x 576)
#define KDR  (2 * 8 * NW)         // kd floats per role
#define MFR  (2 * 8 * NW)         // flags per role
#define STH 10001  // H1 channel stamp base
#define STP 20001  // PRE channel stamp base
#define SPK 50000  // prepack done
#define SF1 50001  // fc1 done
#define SF2 50002  // PRE done
#define SDN 60001  // scan done

typedef unsigned long long u64;

__device__ __forceinline__ float bflo(uint32_t u) { return __uint_as_float(u << 16); }
__device__ __forceinline__ float bfhi(uint32_t u) { return __uint_as_float(u & 0xffff0000u); }
__device__ __forceinline__ uint32_t f2bf(float f) {
    uint32_t x = __float_as_uint(f);
    x += 0x7fffu + ((x >> 16) & 1u);          // RNE
    return x >> 16;
}
__device__ __forceinline__ float sigm(float x)  { return 1.f / (1.f + __expf(-x)); }
__device__ __forceinline__ float tanhf_(float x){ return 1.f - 2.f / (1.f + __expf(2.f * x)); }
__device__ __forceinline__ u64 packvs(float v, int st) {
    return ((u64)(uint32_t)st << 32) | __float_as_uint(v);
}
__device__ __forceinline__ u64 agload(const u64* p) {
    return __hip_atomic_load(p, __ATOMIC_RELAXED, __HIP_MEMORY_SCOPE_AGENT);
}
__device__ __forceinline__ void agstore(u64* p, u64 v) {
    __hip_atomic_store(p, v, __ATOMIC_RELAXED, __HIP_MEMORY_SCOPE_AGENT);
}
__device__ __forceinline__ float agloadf(const float* p) {
    return __hip_atomic_load(p, __ATOMIC_RELAXED, __HIP_MEMORY_SCOPE_AGENT);
}
__device__ __forceinline__ float u2f(u64 v) { return __uint_as_float((uint32_t)v); }

// ---------------------------------------------------------------------------
// LDS layouts (round-3 skeleton; xq machinery removed — it cancels in softmax)
// ---------------------------------------------------------------------------
struct ScanSm {
    uint4 Wr4s[12 * DH_];            // 36,864 B (Wr stays in LDS)
    float sA0[2][N_], sA1[2][N_], sKsc[N_];
    float sAdjN[N_], sSmN[N_];
    float sPre[6 * DS], sXv[DS];
    float sM[DH_], su0[DS], su1[DS], sGc[GC], sHn[DS];
    float sRl[DH_], sP0l[DH_], sP1l[DH_];
    float sRedS[2][8], sSaved[8], sSavedA[2], sSavedS[2];
};
struct WorkSm {
    float sX[DH_];
    float sPv[GC];
};
struct PrologSm {
    float sA[8][768];
    float sRed[3][8][192];
};
struct MlpSm {
    float sH[8][576];
    float sRed[3][8][192];
    float sT[8][192];
};
union SmemAll { ScanSm s; WorkSm w; PrologSm p; MlpSm m; };

// ---------------------------------------------------------------------------
// Prepack slice (identical to round 3).
// ---------------------------------------------------------------------------
__device__ void prepack_slice(int idx,
    const float* __restrict__ wr0, const float* __restrict__ wr1,
    const float* __restrict__ c_wih, const float* __restrict__ c_whh,
    const float* __restrict__ c_bih, const float* __restrict__ c_bhh,
    const float* __restrict__ p_wih, const float* __restrict__ p_whh,
    const float* __restrict__ p_bih, const float* __restrict__ p_bhh,
    float* __restrict__ WpreT, uint32_t* __restrict__ W4,
    uint32_t* __restrict__ Wr4, uint32_t* __restrict__ Wp4w,
    float* __restrict__ biasPre, float* __restrict__ gbx)
{
    for (int l = 0; l < L_; ++l) {
        const float* cwih = c_wih + l * G3 * DH_;
        const float* cwhh = c_whh + l * G3 * DH_;
        const float* pwih = p_wih + l * G3 * DH_;
        const float* pwhh = p_whh + l * G3 * DH_;
        if (l == 0) {
            int k = idx / G6, r = idx - k * G6;
            float w = (r < G3) ? cwih[r * DH_ + k] : pwhh[(r - G3) * DH_ + k];
            WpreT[k * G6 + r] = w;
        }
        if (idx < NW * 27648) {
            int w = idx / 27648, pos = idx % 27648;
            int p4 = pos / 1152, rem = pos % 1152;
            int c2 = rem >> 2, s = rem & 3;
            int p = 4 * p4 + s;
            int j = c2 / DS, dd = c2 % DS;
            int c = 192 * j + DS * w + dd;
            float w0 = (c < G3) ? cwhh[c * DH_ + 2 * p]     : pwih[(c - G3) * DH_ + 2 * p];
            float w1 = (c < G3) ? cwhh[c * DH_ + 2 * p + 1] : pwih[(c - G3) * DH_ + 2 * p + 1];
            W4[l * NW * 27648 + idx] = f2bf(w0) | (f2bf(w1) << 16);
            if (l == 1) {
                int r = c;
                float v0 = (r < G3) ? cwih[r * DH_ + 2 * p]     : pwhh[(r - G3) * DH_ + 2 * p];
                float v1 = (r < G3) ? cwih[r * DH_ + 2 * p + 1] : pwhh[(r - G3) * DH_ + 2 * p + 1];
                Wp4w[idx] = f2bf(v0) | (f2bf(v1) << 16);
            }
        }
        if (idx < NW * 9216) {
            int w = idx / 9216, pos = idx % 9216;
            int kq = pos / 768, rem = pos % 768;
            int d = rem >> 2, s = rem & 3;
            int k = DS * w + 4 * kq + s;
            Wr4[l * NW * 9216 + idx] =
                f2bf(wr0[l * DH_ * DH_ + d * DH_ + k]) |
                (f2bf(wr1[l * DH_ * DH_ + d * DH_ + k]) << 16);
        }
        if (idx < G6) {
            float base = (idx < G3) ? c_bih[l * G3 + idx] : p_bhh[l * G3 + idx - G3];
            float fold = 0.f;
            if (idx < 384)                    fold = c_bhh[l * G3 + idx];
            else if (idx >= G3 && idx < 960)  fold = p_bih[l * G3 + idx - G3];
            biasPre[l * G6 + idx] = base + fold;
        }
        if (idx < 384) {
            gbx[l * 384 + idx] = (idx < DH_) ? c_bhh[l * G3 + 384 + idx]
                                             : p_bih[l * G3 + 384 + (idx - DH_)];
        }
    }
}

// ---------------------------------------------------------------------------
// Global sync among the 96 co-resident WGs via stamped flags.
// ---------------------------------------------------------------------------
__device__ void flag_sync(u64* flags, int wgid, int t, int stamp)
{
    __threadfence();
    __syncthreads();
    if (t == 0) agstore(&flags[wgid], packvs(0.f, stamp));
    if (t < 96) {
        while ((uint32_t)(agload(&flags[t]) >> 32) != (uint32_t)stamp) {}
    }
    __syncthreads();
    __threadfence();
    __syncthreads();
}

// ---------------------------------------------------------------------------
// Prologue: fc1 then PRE-l1. Identical to round 3.
// ---------------------------------------------------------------------------
__device__ void prologue(char* smem, int wgid, int t,
    const float* __restrict__ features, const float* __restrict__ fc1_w,
    const float* __restrict__ fc1_b, const float* __restrict__ WpreT,
    const float* __restrict__ biasPre,
    float* __restrict__ Hcat, float* __restrict__ PREg, u64* __restrict__ Fp)
{
    PrologSm* P = (PrologSm*)smem;
    const int c = t % 192, kg = t / 192;
    for (int tt = wgid; tt < 256; tt += 96) {
        const int r0 = tt * 8;
        for (int q = t; q < 1536; q += 576) {
            int r = q / 192, c4 = q % 192;
            *(float4*)&P->sA[r][4 * c4] = *(const float4*)(features + (size_t)(r0 + r) * 768 + 4 * c4);
        }
        __syncthreads();
        {
            const float* bp = fc1_w + (size_t)(kg * 256) * 192 + c;
            float acc[8] = {0.f, 0.f, 0.f, 0.f, 0.f, 0.f, 0.f, 0.f};
            #pragma unroll 8
            for (int kk = 0; kk < 256; ++kk) {
                float bv = bp[(size_t)kk * 192];
                #pragma unroll
                for (int rr = 0; rr < 8; ++rr) acc[rr] += P->sA[rr][kg * 256 + kk] * bv;
            }
            #pragma unroll
            for (int rr = 0; rr < 8; ++rr) P->sRed[kg][rr][c] = acc[rr];
        }
        __syncthreads();
        if (t < 192) {
            float bv = fc1_b[t];
            #pragma unroll
            for (int rr = 0; rr < 8; ++rr) {
                float v = P->sRed[0][rr][t] + P->sRed[1][rr][t] + P->sRed[2][rr][t] + bv;
                Hcat[(size_t)(r0 + rr) * G3 + t] = fmaxf(v, 0.f);
            }
        }
        __syncthreads();
    }
    flag_sync(Fp + 96, wgid, t, SF1);
    {
        const float bpa = biasPre[t], bpb = biasPre[576 + t];
        for (int tt = wgid; tt < 256; tt += 96) {
            const int r0 = tt * 8;
            for (int q = t; q < 384; q += 576) {
                int r = q / 48, c4 = q % 48;
                *(float4*)&P->sA[r][4 * c4] = *(const float4*)(Hcat + (size_t)(r0 + r) * G3 + 4 * c4);
            }
            __syncthreads();
            {
                const float* b0 = WpreT + t;
                float a0[8] = {0.f,0.f,0.f,0.f,0.f,0.f,0.f,0.f};
                float a1[8] = {0.f,0.f,0.f,0.f,0.f,0.f,0.f,0.f};
                #pragma unroll 4
                for (int k = 0; k < 192; ++k) {
                    float bva = b0[(size_t)k * G6];
                    float bvb = b0[(size_t)k * G6 + 576];
                    #pragma unroll
                    for (int rr = 0; rr < 8; ++rr) {
                        float av = P->sA[rr][k];
                        a0[rr] += av * bva; a1[rr] += av * bvb;
                    }
                }
                #pragma unroll
                for (int rr = 0; rr < 8; ++rr) {
                    PREg[(size_t)(r0 + rr) * G6 + t]       = a0[rr] + bpa;
                    PREg[(size_t)(r0 + rr) * G6 + 576 + t] = a1[rr] + bpb;
                }
            }
            __syncthreads();
        }
    }
    flag_sync(Fp + 192, wgid, t, SF2);
}

// ---------------------------------------------------------------------------
// Epilogue: 3-layer MLP head. Identical to round 3.
// ---------------------------------------------------------------------------
__device__ void mlp_tail(char* smem, int wgid, int t,
    const float* __restrict__ Hcat,
    const float* __restrict__ mw0, const float* __restrict__ mb0,
    const float* __restrict__ mw1, const float* __restrict__ mb1,
    const float* __restrict__ mw2, const float* __restrict__ mb2,
    float* __restrict__ out, u64* __restrict__ Fd)
{
    if (t < 64) {
        while ((uint32_t)(agload(&Fd[t]) >> 32) != (uint32_t)SDN)
            __builtin_amdgcn_s_sleep(2);
    }
    __syncthreads();
    __threadfence();
    __syncthreads();
    MlpSm* M = (MlpSm*)smem;
    const int c = t % 192, kg = t / 192;
    for (int tt = wgid; tt < 256; tt += 96) {
        const int r0 = tt * 8;
        for (int q = t; q < 1152; q += 576) {
            int r = q / 144, c4 = q % 144;
            *(float4*)&M->sH[r][4 * c4] = *(const float4*)(Hcat + (size_t)(r0 + r) * G3 + 4 * c4);
        }
        __syncthreads();
        {
            const float* bp = mw0 + (size_t)(kg * 192) * 192 + c;
            float acc[8] = {0.f,0.f,0.f,0.f,0.f,0.f,0.f,0.f};
            #pragma unroll 8
            for (int kk = 0; kk < 192; ++kk) {
                float bv = bp[(size_t)kk * 192];
                #pragma unroll
                for (int rr = 0; rr < 8; ++rr) acc[rr] += M->sH[rr][kg * 192 + kk] * bv;
            }
            #pragma unroll
            for (int rr = 0; rr < 8; ++rr) M->sRed[kg][rr][c] = acc[rr];
        }
        __syncthreads();
        if (t < 192) {
            float bv = mb0[t];
            #pragma unroll
            for (int rr = 0; rr < 8; ++rr)
                M->sT[rr][t] = fmaxf(M->sRed[0][rr][t] + M->sRed[1][rr][t] + M->sRed[2][rr][t] + bv, 0.f);
        }
        __syncthreads();
        {
            const float* bp = mw1 + (size_t)(kg * 64) * 192 + c;
            float acc[8] = {0.f,0.f,0.f,0.f,0.f,0.f,0.f,0.f};
            #pragma unroll 8
            for (int kk = 0; kk < 64; ++kk) {
                float bv = bp[(size_t)kk * 192];
                #pragma unroll
                for (int rr = 0; rr < 8; ++rr) acc[rr] += M->sT[rr][kg * 64 + kk] * bv;
            }
            #pragma unroll
            for (int rr = 0; rr < 8; ++rr) M->sRed[kg][rr][c] = acc[rr];
        }
        __syncthreads();
        if (t < 192) {
            float bv = mb1[t];
            #pragma unroll
            for (int rr = 0; rr < 8; ++rr)
                M->sH[rr][t] = fmaxf(M->sRed[0][rr][t] + M->sRed[1][rr][t] + M->sRed[2][rr][t] + bv, 0.f);
        }
        __syncthreads();
        {
            const float* bp = mw2 + (size_t)(kg * 64) * 192 + c;
            float acc[8] = {0.f,0.f,0.f,0.f,0.f,0.f,0.f,0.f};
            #pragma unroll 8
            for (int kk = 0; kk < 64; ++kk) {
                float bv = bp[(size_t)kk * 192];
                #pragma unroll
                for (int rr = 0; rr < 8; ++rr) acc[rr] += M->sH[rr][kg * 64 + kk] * bv;
            }
            #pragma unroll
            for (int rr = 0; rr < 8; ++rr) M->sRed[kg][rr][c] = acc[rr];
        }
        __syncthreads();
        if (t < 192) {
            float bv = mb2[t];
            #pragma unroll
            for (int rr = 0; rr < 8; ++rr)
                out[(size_t)(r0 + rr) * 192 + t] =
                    M->sRed[0][rr][t] + M->sRed[1][rr][t] + M->sRed[2][rr][t] + bv;
        }
        __syncthreads();
    }
}

// ---------------------------------------------------------------------------
// Scan body — round-3 phase structure, flag+data transport:
//  P1: t<192 compute R/P0/P1 partials; plain stores to MSG slot + fence
//      t>=384 prefetch row i+1 inputs (Hc/PREc polls for ISL2)
//  P2: t0 publishes stamped flag (covers MSG(i) and kd(i-1)); E(i+1) weights
//  P3: t<384 U(i+1) matvec || t575: poll 3 sibling flags (s_sleep backoff),
//      load 3 kd, compute kdot/e1/invS/appends
//  P4: t<192: bulk-load sibling MSG (agent loads) + combine -> sM
//      t<240 su append; w==0 AsB row i
//  P5: Gc from register-resident weights
//  P6: gates -> hn(i); Hc store; kd(i) plain store
// Parity-double-buffered MSG/kd/flag slots; stamps monotonic per slot (no ABA).
// ---------------------------------------------------------------------------
template<int ISL2>
__device__ void scan_body(
    ScanSm* S, int b, int w, int t,
    const float* __restrict__ xin, float* __restrict__ hout,
    const float* __restrict__ PREg, const float* __restrict__ adj,
    const float* __restrict__ smask,
    const uint32_t* __restrict__ W4l, const uint32_t* __restrict__ Wr4l,
    const float* __restrict__ gbxl, const float* __restrict__ gatwl,
    uint32_t* __restrict__ Hw,
    float* __restrict__ MSGl, float* __restrict__ KdAl, u64* __restrict__ MFl,
    u64* __restrict__ HcW, const u64* __restrict__ HcR,
    const u64* __restrict__ PREcR,
    float* __restrict__ AsB, int sbase)
{
    const int lane = t & 63, wave = t >> 6;
    const int dg0 = w * DS;
    const float* adjB = adj   + (size_t)b * N_ * N_;
    const float* smB  = smask + (size_t)b * N_ * N_;
    const int fi = b * NW;
    const int cB4 = t >> 1, khB4 = t & 1;
    const int w1 = (w + 1) & 3, w2 = (w + 2) & 3, w3 = (w + 3) & 3;

    // Wr -> LDS; Gc weights -> registers
    {
        uint32_t* wr = (uint32_t*)S->Wr4s;
        for (int q = t; q < 9216; q += 576) wr[q] = Wr4l[q];
    }
    uint4 wreg[12];
    {
        const uint4* W4v = (const uint4*)W4l;
        #pragma unroll
        for (int p4 = 0; p4 < 12; ++p4) wreg[p4] = W4v[(12 * khB4 + p4) * GC + cB4];
    }
    float wkv = 0.f, g2b = 0.f, g5b = 0.f;
    if (t < DS) { wkv = gatwl[DH_ + dg0 + t]; g2b = gbxl[dg0 + t]; g5b = gbxl[DH_ + dg0 + t]; }
    if (t < N_) { S->sKsc[t] = 0.f; S->sA0[1][t] = 0.f; S->sA1[1][t] = 0.f; }
    if (t < DS) { S->su0[t] = 0.f; S->su1[t] = 0.f; }
    if (t < 8)  S->sRedS[1][t] = 0.f;
    if (w == 0 && t < N_) AsB[t] = 0.f;

    if (!ISL2) {
        if (t < DS) {
            const float* pre = PREg + (size_t)(b * N_) * G6 + dg0 + t;
            S->sPre[t] = pre[0]; S->sPre[DS + t] = pre[192]; S->sPre[2 * DS + t] = pre[384];
            S->sPre[3 * DS + t] = pre[576]; S->sPre[4 * DS + t] = pre[768]; S->sPre[5 * DS + t] = pre[960];
            S->sXv[t] = xin[(size_t)(b * N_) * G3 + dg0 + t];
        }
        for (int q = t; q < 128; q += 576) {
            if (q < 64)  *(float4*)&S->sAdjN[4 * q] = *(const float4*)(adjB + N_ + 4 * q);
            else { int q2 = q - 64; *(float4*)&S->sSmN[4 * q2] = *(const float4*)(smB + N_ + 4 * q2); }
        }
    } else {
        for (int q = t; q < 320; q += 576) {
            if (q < 64)       *(float4*)&S->sAdjN[4 * q] = *(const float4*)(adjB + N_ + 4 * q);
            else if (q < 128) { int q2 = q - 64;  *(float4*)&S->sSmN[4 * q2] = *(const float4*)(smB + N_ + 4 * q2); }
            else if (q < 176) {
                int d = q - 128;
                const u64* p = HcR + ((size_t)(b * N_) * NW + w) * DS + d;
                u64 v; do { v = agload(p); } while ((uint32_t)(v >> 32) != (uint32_t)STH);
                S->sXv[d] = __uint_as_float((uint32_t)v);
            } else {
                int qq = q - 176;
                const u64* p = PREcR + ((size_t)(b * N_) * NW + w) * 144 + qq;
                u64 v; do { v = agload(p); } while ((uint32_t)(v >> 32) != (uint32_t)STP);
                uint32_t pl = (uint32_t)v;
                S->sPre[2 * qq] = bflo(pl); S->sPre[2 * qq + 1] = bfhi(pl);
            }
        }
    }
    __syncthreads();
    // ---- step 0 (no attention) ----
    {
        float hn = 0.f;
        if (t < DS) {
            float xv = S->sXv[t];
            float r1 = sigm(S->sPre[t]), z1 = sigm(S->sPre[DS + t]);
            float n1 = tanhf_(S->sPre[2 * DS + t] + r1 * g2b);
            float Cv = (1.f - z1) * n1;
            float r2 = sigm(S->sPre[3 * DS + t]), z2 = sigm(S->sPre[4 * DS + t]);
            float n2 = tanhf_(g5b + r2 * S->sPre[5 * DS + t]);
            hn = Cv + (1.f - z2) * n2 + z2 * xv;
            S->sHn[t] = hn;
            hout[(size_t)(b * N_) * G3 + dg0 + t] = hn;
            if (!ISL2) HcW[((size_t)(b * N_) * NW + w) * DS + t] = packvs(hn, STH);
        }
        if (t == 0) { S->sSavedA[1] = S->sAdjN[0]; S->sSavedS[1] = S->sSmN[0]; }
        if (wave == 0) {
            float v = hn * wkv;
            #pragma unroll
            for (int o = 32; o; o >>= 1) v += __shfl_xor(v, o);
            if (lane == 0) { S->sSaved[6] = v; KdAl[fi + w] = v; }   // parity 0 slot
        }
    }
    __syncthreads();
    if (t < KD) Hw[(size_t)t * N_] = f2bf(S->sHn[2 * t]) | (f2bf(S->sHn[2 * t + 1]) << 16);
    __syncthreads();

    for (int i = 1; i < N_; ++i) {
        const int row = b * N_ + i;
        const int stamp = sbase + i;
        const int pp = i & 1, pn = pp ^ 1;

        // ---- P1: raw partials -> LDS + plain MSG stores + fence; prefetch ---
        if (t < DH_) {
            float rr = 0.f, p0 = 0.f, p1 = 0.f;
            #pragma unroll 4
            for (int kq = 0; kq < 12; ++kq) {
                uint4 wv = S->Wr4s[kq * DH_ + t];
                const int k0 = 4 * kq;
                float lo, hi;
                lo = bflo(wv.x); hi = bfhi(wv.x);
                rr = fmaf(S->su0[k0 + 0], lo, rr); rr = fmaf(S->su1[k0 + 0], hi, rr);
                p0 = fmaf(S->sHn[k0 + 0], lo, p0); p1 = fmaf(S->sHn[k0 + 0], hi, p1);
                lo = bflo(wv.y); hi = bfhi(wv.y);
                rr = fmaf(S->su0[k0 + 1], lo, rr); rr = fmaf(S->su1[k0 + 1], hi, rr);
                p0 = fmaf(S->sHn[k0 + 1], lo, p0); p1 = fmaf(S->sHn[k0 + 1], hi, p1);
                lo = bflo(wv.z); hi = bfhi(wv.z);
                rr = fmaf(S->su0[k0 + 2], lo, rr); rr = fmaf(S->su1[k0 + 2], hi, rr);
                p0 = fmaf(S->sHn[k0 + 2], lo, p0); p1 = fmaf(S->sHn[k0 + 2], hi, p1);
                lo = bflo(wv.w); hi = bfhi(wv.w);
                rr = fmaf(S->su0[k0 + 3], lo, rr); rr = fmaf(S->su1[k0 + 3], hi, rr);
                p0 = fmaf(S->sHn[k0 + 3], lo, p0); p1 = fmaf(S->sHn[k0 + 3], hi, p1);
            }
            S->sRl[t] = rr; S->sP0l[t] = p0; S->sP1l[t] = p1;
            float* myMSG = MSGl + (size_t)(pp * 32 + fi + w) * 576;
            myMSG[t] = rr; myMSG[192 + t] = p0; myMSG[384 + t] = p1;
            __threadfence();                       // release own MSG + prior kd store
        } else if (t >= 384) {
            const int u = t - 384;
            const int inx = (i + 1 < N_) ? i + 1 : N_ - 1;
            if (!ISL2) {
                for (int qq = u; qq < 212; qq += 192) {
                    if (qq < 64)
                        *(float4*)&S->sAdjN[4 * qq] = *(const float4*)(adjB + (size_t)inx * N_ + 4 * qq);
                    else if (qq < 128) { int q2 = qq - 64;
                        *(float4*)&S->sSmN[4 * q2] = *(const float4*)(smB + (size_t)inx * N_ + 4 * q2); }
                    else if (qq < 140) { int q2 = qq - 128;
                        *(float4*)&S->sXv[4 * q2] = *(const float4*)(xin + (size_t)row * G3 + dg0 + 4 * q2); }
                    else { int q2 = qq - 140; int g = q2 / 12, o = q2 - 12 * g;
                        *(float4*)&S->sPre[g * DS + 4 * o] =
                            *(const float4*)(PREg + (size_t)row * G6 + g * DH_ + dg0 + 4 * o); }
                }
            } else {
                for (int qq = u; qq < 320; qq += 192) {
                    if (qq < 64)
                        *(float4*)&S->sAdjN[4 * qq] = *(const float4*)(adjB + (size_t)inx * N_ + 4 * qq);
                    else if (qq < 128) { int q2 = qq - 64;
                        *(float4*)&S->sSmN[4 * q2] = *(const float4*)(smB + (size_t)inx * N_ + 4 * q2); }
                    else if (qq < 176) {
                        int d = qq - 128;
                        const u64* p = HcR + ((size_t)row * NW + w) * DS + d;
                        u64 v; do { v = agload(p); } while ((uint32_t)(v >> 32) != (uint32_t)(STH + i));
                        S->sXv[d] = __uint_as_float((uint32_t)v);
                    } else {
                        int q2 = qq - 176;
                        const u64* p = PREcR + ((size_t)row * NW + w) * 144 + q2;
                        u64 v; do { v = agload(p); } while ((uint32_t)(v >> 32) != (uint32_t)(STP + i));
                        uint32_t pl = (uint32_t)v;
                        S->sPre[2 * q2] = bflo(pl); S->sPre[2 * q2 + 1] = bfhi(pl);
                    }
                }
            }
        }
        __syncthreads();                                         // B1

        // ---- P2: publish flag; E(i+1) weights for j <= i-2 ------------------
        if (t == 0) agstore(&MFl[pp * 32 + fi + w], packvs(0.f, stamp));
        if (t < N_) {
            float e = 0.f;
            if (t == i) { S->sSavedA[pn] = S->sAdjN[t]; S->sSavedS[pn] = S->sSmN[t]; }
            if (t < i - 1 && S->sAdjN[t] > 0.5f) e = __expf(S->sKsc[t]);
            float b0 = e * S->sSmN[t];
            S->sA0[pn][t] = b0; S->sA1[pn][t] = e - b0;
            float ps = e;
            #pragma unroll
            for (int o = 32; o; o >>= 1) ps += __shfl_xor(ps, o);
            if (lane == 0) S->sRedS[pn][wave] = ps;
        }
        __syncthreads();                                         // B2

        // ---- P3: U(i+1) matvec || flag poll + kdot scalars ------------------
        if (t < 384) {
            const int ilim = i - 1;                              // j <= i-2
            const int kd = t >> 4, jp = t & 15;
            const uint32_t* hp = Hw + (size_t)kd * N_;
            float u0l = 0.f, u0h = 0.f, u1l = 0.f, u1h = 0.f;
            int j = jp;
            while (j + 48 < ilim) {
                uint32_t h0 = hp[j], h1 = hp[j + 16], h2 = hp[j + 32], h3 = hp[j + 48];
                float b0, b1;
                b0 = S->sA0[pn][j];      b1 = S->sA1[pn][j];
                u0l = fmaf(b0, bflo(h0), u0l); u0h = fmaf(b0, bfhi(h0), u0h);
                u1l = fmaf(b1, bflo(h0), u1l); u1h = fmaf(b1, bfhi(h0), u1h);
                b0 = S->sA0[pn][j + 16]; b1 = S->sA1[pn][j + 16];
                u0l = fmaf(b0, bflo(h1), u0l); u0h = fmaf(b0, bfhi(h1), u0h);
                u1l = fmaf(b1, bflo(h1), u1l); u1h = fmaf(b1, bfhi(h1), u1h);
                b0 = S->sA0[pn][j + 32]; b1 = S->sA1[pn][j + 32];
                u0l = fmaf(b0, bflo(h2), u0l); u0h = fmaf(b0, bfhi(h2), u0h);
                u1l = fmaf(b1, bflo(h2), u1l); u1h = fmaf(b1, bfhi(h2), u1h);
                b0 = S->sA0[pn][j + 48]; b1 = S->sA1[pn][j + 48];
                u0l = fmaf(b0, bflo(h3), u0l); u0h = fmaf(b0, bfhi(h3), u0h);
                u1l = fmaf(b1, bflo(h3), u1l); u1h = fmaf(b1, bfhi(h3), u1h);
                j += 64;
            }
            for (; j < ilim; j += 16) {
                uint32_t hv = hp[j];
                float b0 = S->sA0[pn][j], b1 = S->sA1[pn][j];
                u0l = fmaf(b0, bflo(hv), u0l); u0h = fmaf(b0, bfhi(hv), u0h);
                u1l = fmaf(b1, bflo(hv), u1l); u1h = fmaf(b1, bfhi(hv), u1h);
            }
            #pragma unroll
            for (int o = 1; o <= 8; o <<= 1) {
                u0l += __shfl_xor(u0l, o); u0h += __shfl_xor(u0h, o);
                u1l += __shfl_xor(u1l, o); u1h += __shfl_xor(u1h, o);
            }
            if (jp == 0) {
                S->su0[2 * kd] = u0l; S->su0[2 * kd + 1] = u0h;
                S->su1[2 * kd] = u1l; S->su1[2 * kd + 1] = u1h;
            }
        } else if (t == 575) {
            const uint32_t ex = (uint32_t)stamp;
            const u64* f1 = &MFl[pp * 32 + fi + w1];
            const u64* f2 = &MFl[pp * 32 + fi + w2];
            const u64* f3 = &MFl[pp * 32 + fi + w3];
            for (;;) {
                u64 a = agload(f1), bq = agload(f2), c = agload(f3);
                if ((uint32_t)(a >> 32) == ex && (uint32_t)(bq >> 32) == ex &&
                    (uint32_t)(c >> 32) == ex) break;
                __builtin_amdgcn_s_sleep(1);
            }
            const int kpar = (i - 1) & 1;
            float kdot = S->sSaved[6]
                       + agloadf(&KdAl[kpar * 32 + fi + w1])
                       + agloadf(&KdAl[kpar * 32 + fi + w2])
                       + agloadf(&KdAl[kpar * 32 + fi + w3]);
            float adj1 = S->sSavedA[pp], sm1 = S->sSavedS[pp];
            float er = __expf(kdot);
            float e1 = (adj1 > 0.5f) ? er : 0.f;
            float Ssum = S->sRedS[pp][0] + S->sRedS[pp][1] + S->sRedS[pp][2]
                       + S->sRedS[pp][3] + S->sRedS[pp][4] + e1;
            S->sKsc[i - 1] = kdot;
            float invS = 1.f / Ssum;
            float e1c0 = e1 * sm1, e1c1 = e1 - e1c0;
            S->sSaved[2] = invS;
            S->sSaved[4] = e1c0; S->sSaved[5] = e1c1;
            S->sA0[pp][i - 1] = e1c0; S->sA1[pp][i - 1] = e1c1;
            // append j = i-1 term for query i+1
            float adjn = S->sAdjN[i - 1], smn = S->sSmN[i - 1];
            float en = (adjn > 0.5f) ? er : 0.f;
            float n0 = en * smn;
            S->sA0[pn][i - 1] = n0; S->sA1[pn][i - 1] = en - n0;
            S->sRedS[pn][4] = en;
        }
        __syncthreads();                                         // B3

        // ---- P4: bulk-load sibling MSG + combine; su append; AsB row i ------
        if (t < DH_) {
            const float* m1 = MSGl + (size_t)(pp * 32 + fi + w1) * 576;
            const float* m2 = MSGl + (size_t)(pp * 32 + fi + w2) * 576;
            const float* m3 = MSGl + (size_t)(pp * 32 + fi + w3) * 576;
            float rs = S->sRl[t]  + agloadf(m1 + t)       + agloadf(m2 + t)       + agloadf(m3 + t);
            float p0 = S->sP0l[t] + agloadf(m1 + 192 + t) + agloadf(m2 + 192 + t) + agloadf(m3 + 192 + t);
            float p1 = S->sP1l[t] + agloadf(m1 + 384 + t) + agloadf(m2 + 384 + t) + agloadf(m3 + 384 + t);
            S->sM[t] = (rs + S->sSaved[4] * p0 + S->sSaved[5] * p1) * S->sSaved[2];
        } else if (t < 192 + DS) {
            const int k = t - 192;
            float a0 = S->sA0[pn][i - 1], a1 = S->sA1[pn][i - 1];
            S->su0[k] += a0 * S->sHn[k];
            S->su1[k] += a1 * S->sHn[k];
        } else if (w == 0 && t >= 256 && t < 512) {
            const int j = t - 256;
            AsB[(size_t)i * N_ + j] = (S->sA0[pp][j] + S->sA1[pp][j]) * S->sSaved[2];
        }
        __syncthreads();                                         // B4

        // ---- P5: Gc from register-resident weights --------------------------
        {
            float g = 0.f;
            #pragma unroll
            for (int p4 = 0; p4 < 12; ++p4) {
                const uint4 wv = wreg[p4];
                const int m0 = 8 * (12 * khB4 + p4);
                g = fmaf(S->sM[m0 + 0], bflo(wv.x), g); g = fmaf(S->sM[m0 + 1], bfhi(wv.x), g);
                g = fmaf(S->sM[m0 + 2], bflo(wv.y), g); g = fmaf(S->sM[m0 + 3], bfhi(wv.y), g);
                g = fmaf(S->sM[m0 + 4], bflo(wv.z), g); g = fmaf(S->sM[m0 + 5], bfhi(wv.z), g);
                g = fmaf(S->sM[m0 + 6], bflo(wv.w), g); g = fmaf(S->sM[m0 + 7], bfhi(wv.w), g);
            }
            g += __shfl_xor(g, 1);
            if (khB4 == 0) S->sGc[cB4] = g;
        }
        __syncthreads();                                         // B5

        // ---- P6: gates -> hn(i); Hc store; kd(i) plain store; Hw pack -------
        {
            float hn = 0.f;
            if (t < DS) {
                float Mv = S->sM[dg0 + t];
                float r1 = sigm(S->sPre[t] + S->sGc[t]);
                float z1 = sigm(S->sPre[DS + t] + S->sGc[DS + t]);
                float n1 = tanhf_(S->sPre[2 * DS + t] + r1 * (S->sGc[2 * DS + t] + g2b));
                float Cv = (1.f - z1) * n1 + z1 * Mv;
                float r2 = sigm(S->sGc[3 * DS + t] + S->sPre[3 * DS + t]);
                float z2 = sigm(S->sGc[4 * DS + t] + S->sPre[4 * DS + t]);
                float n2 = tanhf_(S->sGc[5 * DS + t] + g5b + r2 * S->sPre[5 * DS + t]);
                hn = Cv + (1.f - z2) * n2 + z2 * S->sXv[t];
                S->sHn[t] = hn;
                hout[(size_t)row * G3 + dg0 + t] = hn;
                if (!ISL2) HcW[((size_t)row * NW + w) * DS + t] = packvs(hn, STH + i);
            }
            if (wave == 0) {
                float v = hn * wkv;
                #pragma unroll
                for (int o = 32; o; o >>= 1) v += __shfl_xor(v, o);
                if (lane == 0) { S->sSaved[6] = v; KdAl[(i & 1) * 32 + fi + w] = v; }
            }
            if (t < KD) Hw[(size_t)t * N_ + i] = f2bf(S->sHn[2 * t]) | (f2bf(S->sHn[2 * t + 1]) << 16);
        }
        __syncthreads();                                         // B6
    }
}

// ---------------------------------------------------------------------------
// PRE worker — round 3 minus xq machinery.
// ---------------------------------------------------------------------------
__device__ void worker_body(WorkSm* Wm, int b, int w, int t,
    const uint32_t* __restrict__ Wp4g, const float* __restrict__ bias2,
    const u64* __restrict__ HcR, u64* __restrict__ PREcW)
{
    const int c = t >> 1, kh = t & 1;
    uint4 wpreg[12];
    {
        const uint4* v4 = (const uint4*)Wp4g;
        #pragma unroll
        for (int p4 = 0; p4 < 12; ++p4) wpreg[p4] = v4[(12 * kh + p4) * GC + c];
    }
    float bv = 0.f;
    if (kh == 0) bv = bias2[192 * (c / DS) + w * DS + (c % DS)];
    for (int i = 0; i < N_; ++i) {
        if (t < DH_) {
            const u64* p = HcR + ((size_t)(b * N_ + i) * NW + (t / DS)) * DS + (t % DS);
            u64 v; do { v = agload(p); } while ((uint32_t)(v >> 32) != (uint32_t)(STH + i));
            Wm->sX[t] = __uint_as_float((uint32_t)v);
        }
        __syncthreads();
        {
            float g = 0.f;
            #pragma unroll
            for (int p4 = 0; p4 < 12; ++p4) {
                const uint4 wv = wpreg[p4];
                const int m0 = 8 * (12 * kh + p4);
                g = fmaf(Wm->sX[m0 + 0], bflo(wv.x), g); g = fmaf(Wm->sX[m0 + 1], bfhi(wv.x), g);
                g = fmaf(Wm->sX[m0 + 2], bflo(wv.y), g); g = fmaf(Wm->sX[m0 + 3], bfhi(wv.y), g);
                g = fmaf(Wm->sX[m0 + 4], bflo(wv.z), g); g = fmaf(Wm->sX[m0 + 5], bfhi(wv.z), g);
                g = fmaf(Wm->sX[m0 + 6], bflo(wv.w), g); g = fmaf(Wm->sX[m0 + 7], bfhi(wv.w), g);
            }
            g += __shfl_xor(g, 1);
            if (kh == 0) Wm->sPv[c] = g + bv;
        }
        __syncthreads();
        if (t < 144) {
            u64 v = ((u64)(uint32_t)(STP + i) << 32)
                  | f2bf(Wm->sPv[2 * t]) | (f2bf(Wm->sPv[2 * t + 1]) << 16);
            agstore(&PREcW[((size_t)(b * N_ + i) * NW + w) * 144 + t], v);
        }
        __syncthreads();
    }
}

// ---------------------------------------------------------------------------
// Single fused kernel.
// ---------------------------------------------------------------------------
__global__ __launch_bounds__(576, 1) void pipeline_kernel(
    const float* __restrict__ features, const float* __restrict__ fc1_w,
    const float* __restrict__ fc1_b,
    const float* __restrict__ adj, const float* __restrict__ smask,
    const float* __restrict__ gatw,
    const float* __restrict__ wr0, const float* __restrict__ wr1,
    const float* __restrict__ c_wih, const float* __restrict__ c_whh,
    const float* __restrict__ c_bih, const float* __restrict__ c_bhh,
    const float* __restrict__ p_wih, const float* __restrict__ p_whh,
    const float* __restrict__ p_bih, const float* __restrict__ p_bhh,
    const float* __restrict__ mw0, const float* __restrict__ mb0,
    const float* __restrict__ mw1, const float* __restrict__ mb1,
    const float* __restrict__ mw2, const float* __restrict__ mb2,
    float* __restrict__ Hcat, float* __restrict__ PREg,
    float* __restrict__ WpreT, uint32_t* __restrict__ W4,
    uint32_t* __restrict__ Wr4, uint32_t* __restrict__ Wp4w,
    float* __restrict__ biasPre, float* __restrict__ gbx,
    uint32_t* __restrict__ Hb,
    float* __restrict__ MSG, float* __restrict__ KdA, u64* __restrict__ MFlag,
    u64* __restrict__ Hc, u64* __restrict__ PREc,
    u64* __restrict__ Fp, u64* __restrict__ Fd,
    float* __restrict__ out)
{
    __shared__ __align__(16) char smem[sizeof(SmemAll)];
    const int blk = blockIdx.x, t = threadIdx.x;
    const int wgid = blk;
    const int b = blk & 7, r12 = blk >> 3;
    const int role = r12 >> 2, w = r12 & 3;

    // ---- prepack slices (all WGs) ------------------------------------------
    for (int j = 0; j < 4; ++j) {
        int idx = wgid * 576 + t + 55296 * j;
        prepack_slice(idx, wr0, wr1, c_wih, c_whh, c_bih, c_bhh,
                      p_wih, p_whh, p_bih, p_bhh,
                      WpreT, W4, Wr4, Wp4w, biasPre, gbx);
    }
    flag_sync(Fp, wgid, t, SPK);

    // ---- fc1 + PRE-l1 prologue ---------------------------------------------
    prologue(smem, wgid, t, features, fc1_w, fc1_b, WpreT, biasPre,
             Hcat, PREg, Fp);

    // ---- roles -------------------------------------------------------------
    float* As = out + 393216;
    if (role == 0) {
        scan_body<0>((ScanSm*)smem, b, w, t,
            Hcat, Hcat + 192, PREg, adj, smask,
            W4, Wr4, gbx, gatw,
            Hb + (size_t)(b * NW + w) * KD * N_,
            MSG, KdA, MFlag,
            Hc, nullptr, nullptr,
            As + (size_t)b * (L_ * N_ * N_), 1);
        __threadfence();
        __syncthreads();
        if (t == 0) agstore(&Fd[b * 8 + w], packvs(0.f, SDN));
    } else if (role == 2) {
        scan_body<1>((ScanSm*)smem, b, w, t,
            nullptr, Hcat + 384, nullptr, adj, smask,
            W4 + NW * 27648, Wr4 + NW * 9216, gbx + 384, gatw + 384,
            Hb + (size_t)(32 + b * NW + w) * KD * N_,
            MSG + MSGR, KdA + KDR, MFlag + MFR,
            nullptr, Hc, PREc,
            As + (size_t)b * (L_ * N_ * N_) + N_ * N_, 30001);
        __threadfence();
        __syncthreads();
        if (t == 0) agstore(&Fd[b * 8 + 4 + w], packvs(0.f, SDN));
    } else {
        worker_body((WorkSm*)smem, b, w, t,
            Wp4w + (size_t)w * 27648, biasPre + G6,
            Hc, PREc);
    }

    // ---- MLP epilogue (all WGs) --------------------------------------------
    mlp_tail(smem, wgid, t, Hcat, mw0, mb0, mw1, mb1, mw2, mb2, out, Fd);
}

// ---------------------------------------------------------------------------
extern "C" void kernel_launch(void* const* d_in, const int* in_sizes, int n_in,
                              void* d_out, int out_size, void* d_ws, size_t ws_size,
                              hipStream_t stream)
{
    const float* features = (const float*)d_in[0];
    const float* adj      = (const float*)d_in[1];
    const float* smask    = (const float*)d_in[2];
    const float* fc1_w = (const float*)d_in[5];
    const float* fc1_b = (const float*)d_in[6];
    const float* gat_w = (const float*)d_in[7];
    const float* wr0   = (const float*)d_in[9];
    const float* wr1   = (const float*)d_in[10];
    const float* c_wih = (const float*)d_in[11];
    const float* c_whh = (const float*)d_in[12];
    const float* c_bih = (const float*)d_in[13];
    const float* c_bhh = (const float*)d_in[14];
    const float* p_wih = (const float*)d_in[15];
    const float* p_whh = (const float*)d_in[16];
    const float* p_bih = (const float*)d_in[17];
    const float* p_bhh = (const float*)d_in[18];
    const float* mw0 = (const float*)d_in[19];
    const float* mb0 = (const float*)d_in[20];
    const float* mw1 = (const float*)d_in[21];
    const float* mb1 = (const float*)d_in[22];
    const float* mw2 = (const float*)d_in[23];
    const float* mb2 = (const float*)d_in[24];
    float* out = (float*)d_out;

    char* wsb = (char*)d_ws;
    size_t off = 0;
    auto carve = [&](size_t bytes) -> char* {
        char* p = wsb + off;
        off = (off + bytes + 255) & ~(size_t)255;
        return p;
    };
    float* Hcat     = (float*)carve(2048ull * 576 * 4);
    float* PREg     = (float*)carve(2048ull * 1152 * 4);
    float* WpreT    = (float*)carve(192ull * 1152 * 4);
    uint32_t* W4    = (uint32_t*)carve(2ull * NW * 27648 * 4);
    uint32_t* Wr4   = (uint32_t*)carve(2ull * NW * 9216 * 4);
    uint32_t* Wp4w  = (uint32_t*)carve((size_t)NW * 27648 * 4);
    float* biasPre  = (float*)carve(2ull * 1152 * 4);
    float* gbx      = (float*)carve(2ull * 384 * 4);
    uint32_t* Hb    = (uint32_t*)carve(64ull * KD * 256 * 4);
    float* MSG      = (float*)carve(2ull * MSGR * 4);    // 2 roles
    float* KdA      = (float*)carve(2ull * KDR * 4);     // 2 roles
    u64* MFlag      = (u64*)carve(2ull * MFR * 8);       // 2 roles
    u64* Hc         = (u64*)carve(8ull * 256 * NW * DS * 8);
    u64* PREc       = (u64*)carve(8ull * 256 * NW * 144 * 8);
    u64* Fp         = (u64*)carve(288ull * 8);
    u64* Fd         = (u64*)carve(64ull * 8);

    pipeline_kernel<<<dim3(96), 576, 0, stream>>>(
        features, fc1_w, fc1_b, adj, smask, gat_w,
        wr0, wr1, c_wih, c_whh, c_bih, c_bhh, p_wih, p_whh, p_bih, p_bhh,
        mw0, mb0, mw1, mb1, mw2, mb2,
        Hcat, PREg, WpreT, W4, Wr4, Wp4w, biasPre, gbx,
        Hb, MSG, KdA, MFlag, Hc, PREc, Fp, Fd, out);
}

// Round 7
// 1652.143 us; speedup vs baseline: 2.3825x; 1.4307x over previous
//
#include <hip/hip_runtime.h>
#include <stdint.h>

#define B_  8
#define N_  256
#define DH_ 192
#define L_  2
#define G3  576
#define G6  1152
#define NW  4      // WGs per batch per role
#define DS  48     // d-slice per WG
#define KD  24     // H-history dwords per WG (48 bf16)
#define GC  288    // g-cols per WG
#define MPSZ (8 * NW * DH_ * 3)   // MPs entries per parity per role
#define KDSZ (8 * NW)             // Kd entries per parity per role
#define STH 10001  // H1 channel stamp base
#define STP 20001  // PRE channel stamp base
#define SPK 50000  // prepack done
#define SF1 50001  // fc1 done
#define SF2 50002  // PRE done
#define SDN 60001  // scan done

typedef unsigned long long u64;

__device__ __forceinline__ float bflo(uint32_t u) { return __uint_as_float(u << 16); }
__device__ __forceinline__ float bfhi(uint32_t u) { return __uint_as_float(u & 0xffff0000u); }
__device__ __forceinline__ uint32_t f2bf(float f) {
    uint32_t x = __float_as_uint(f);
    x += 0x7fffu + ((x >> 16) & 1u);          // RNE
    return x >> 16;
}
__device__ __forceinline__ float sigm(float x)  { return 1.f / (1.f + __expf(-x)); }
__device__ __forceinline__ float tanhf_(float x){ return 1.f - 2.f / (1.f + __expf(2.f * x)); }
__device__ __forceinline__ u64 packvs(float v, int st) {
    return ((u64)(uint32_t)st << 32) | __float_as_uint(v);
}
__device__ __forceinline__ u64 agload(const u64* p) {
    return __hip_atomic_load(p, __ATOMIC_RELAXED, __HIP_MEMORY_SCOPE_AGENT);
}
__device__ __forceinline__ void agstore(u64* p, u64 v) {
    __hip_atomic_store(p, v, __ATOMIC_RELAXED, __HIP_MEMORY_SCOPE_AGENT);
}
__device__ __forceinline__ float u2f(u64 v) { return __uint_as_float((uint32_t)v); }

// Workgroup barrier WITHOUT the global-store drain: LDS handoffs only need
// lgkmcnt(0); global stamped-channel stores have no in-WG consumer and may
// drain lazily. "memory" clobbers pin LDS ops on both sides of the barrier.
__device__ __forceinline__ void wg_barrier() {
    asm volatile("s_waitcnt lgkmcnt(0)" ::: "memory");
    __builtin_amdgcn_s_barrier();
    asm volatile("" ::: "memory");
}

// ---------------------------------------------------------------------------
// LDS layouts (round-3 skeleton; xq machinery removed — cancels in softmax)
// ---------------------------------------------------------------------------
struct ScanSm {
    uint4 Wr4s[12 * DH_];            // 36,864 B (Wr stays in LDS)
    float sA0[2][N_], sA1[2][N_], sKsc[N_];
    float sAdjN[N_], sSmN[N_];
    float sPre[6 * DS], sXv[DS];
    float sM[DH_], su0[DS], su1[DS], sGc[GC], sHn[DS];
    float sRl[DH_], sP0l[DH_], sP1l[DH_];
    float sRedS[2][8], sSaved[8], sSavedA[2], sSavedS[2];
};
struct WorkSm {
    float sX[DH_];
    float sPv[GC];
};
struct PrologSm {
    float sA[8][768];
    float sRed[3][8][192];
};
struct MlpSm {
    float sH[8][576];
    float sRed[3][8][192];
    float sT[8][192];
};
union SmemAll { ScanSm s; WorkSm w; PrologSm p; MlpSm m; };

// ---------------------------------------------------------------------------
// Prepack slice (identical to round 3).
// ---------------------------------------------------------------------------
__device__ void prepack_slice(int idx,
    const float* __restrict__ wr0, const float* __restrict__ wr1,
    const float* __restrict__ c_wih, const float* __restrict__ c_whh,
    const float* __restrict__ c_bih, const float* __restrict__ c_bhh,
    const float* __restrict__ p_wih, const float* __restrict__ p_whh,
    const float* __restrict__ p_bih, const float* __restrict__ p_bhh,
    float* __restrict__ WpreT, uint32_t* __restrict__ W4,
    uint32_t* __restrict__ Wr4, uint32_t* __restrict__ Wp4w,
    float* __restrict__ biasPre, float* __restrict__ gbx)
{
    for (int l = 0; l < L_; ++l) {
        const float* cwih = c_wih + l * G3 * DH_;
        const float* cwhh = c_whh + l * G3 * DH_;
        const float* pwih = p_wih + l * G3 * DH_;
        const float* pwhh = p_whh + l * G3 * DH_;
        if (l == 0) {
            int k = idx / G6, r = idx - k * G6;
            float w = (r < G3) ? cwih[r * DH_ + k] : pwhh[(r - G3) * DH_ + k];
            WpreT[k * G6 + r] = w;
        }
        if (idx < NW * 27648) {
            int w = idx / 27648, pos = idx % 27648;
            int p4 = pos / 1152, rem = pos % 1152;
            int c2 = rem >> 2, s = rem & 3;
            int p = 4 * p4 + s;
            int j = c2 / DS, dd = c2 % DS;
            int c = 192 * j + DS * w + dd;
            float w0 = (c < G3) ? cwhh[c * DH_ + 2 * p]     : pwih[(c - G3) * DH_ + 2 * p];
            float w1 = (c < G3) ? cwhh[c * DH_ + 2 * p + 1] : pwih[(c - G3) * DH_ + 2 * p + 1];
            W4[l * NW * 27648 + idx] = f2bf(w0) | (f2bf(w1) << 16);
            if (l == 1) {
                int r = c;
                float v0 = (r < G3) ? cwih[r * DH_ + 2 * p]     : pwhh[(r - G3) * DH_ + 2 * p];
                float v1 = (r < G3) ? cwih[r * DH_ + 2 * p + 1] : pwhh[(r - G3) * DH_ + 2 * p + 1];
                Wp4w[idx] = f2bf(v0) | (f2bf(v1) << 16);
            }
        }
        if (idx < NW * 9216) {
            int w = idx / 9216, pos = idx % 9216;
            int kq = pos / 768, rem = pos % 768;
            int d = rem >> 2, s = rem & 3;
            int k = DS * w + 4 * kq + s;
            Wr4[l * NW * 9216 + idx] =
                f2bf(wr0[l * DH_ * DH_ + d * DH_ + k]) |
                (f2bf(wr1[l * DH_ * DH_ + d * DH_ + k]) << 16);
        }
        if (idx < G6) {
            float base = (idx < G3) ? c_bih[l * G3 + idx] : p_bhh[l * G3 + idx - G3];
            float fold = 0.f;
            if (idx < 384)                    fold = c_bhh[l * G3 + idx];
            else if (idx >= G3 && idx < 960)  fold = p_bih[l * G3 + idx - G3];
            biasPre[l * G6 + idx] = base + fold;
        }
        if (idx < 384) {
            gbx[l * 384 + idx] = (idx < DH_) ? c_bhh[l * G3 + 384 + idx]
                                             : p_bih[l * G3 + 384 + (idx - DH_)];
        }
    }
}

// ---------------------------------------------------------------------------
// Global sync among the 96 co-resident WGs via stamped flags.
// ---------------------------------------------------------------------------
__device__ void flag_sync(u64* flags, int wgid, int t, int stamp)
{
    __threadfence();
    __syncthreads();
    if (t == 0) agstore(&flags[wgid], packvs(0.f, stamp));
    if (t < 96) {
        while ((uint32_t)(agload(&flags[t]) >> 32) != (uint32_t)stamp) {}
    }
    __syncthreads();
    __threadfence();
    __syncthreads();
}

// ---------------------------------------------------------------------------
// Prologue: fc1 then PRE-l1. Identical to round 3.
// ---------------------------------------------------------------------------
__device__ void prologue(char* smem, int wgid, int t,
    const float* __restrict__ features, const float* __restrict__ fc1_w,
    const float* __restrict__ fc1_b, const float* __restrict__ WpreT,
    const float* __restrict__ biasPre,
    float* __restrict__ Hcat, float* __restrict__ PREg, u64* __restrict__ Fp)
{
    PrologSm* P = (PrologSm*)smem;
    const int c = t % 192, kg = t / 192;
    for (int tt = wgid; tt < 256; tt += 96) {
        const int r0 = tt * 8;
        for (int q = t; q < 1536; q += 576) {
            int r = q / 192, c4 = q % 192;
            *(float4*)&P->sA[r][4 * c4] = *(const float4*)(features + (size_t)(r0 + r) * 768 + 4 * c4);
        }
        __syncthreads();
        {
            const float* bp = fc1_w + (size_t)(kg * 256) * 192 + c;
            float acc[8] = {0.f, 0.f, 0.f, 0.f, 0.f, 0.f, 0.f, 0.f};
            #pragma unroll 8
            for (int kk = 0; kk < 256; ++kk) {
                float bv = bp[(size_t)kk * 192];
                #pragma unroll
                for (int rr = 0; rr < 8; ++rr) acc[rr] += P->sA[rr][kg * 256 + kk] * bv;
            }
            #pragma unroll
            for (int rr = 0; rr < 8; ++rr) P->sRed[kg][rr][c] = acc[rr];
        }
        __syncthreads();
        if (t < 192) {
            float bv = fc1_b[t];
            #pragma unroll
            for (int rr = 0; rr < 8; ++rr) {
                float v = P->sRed[0][rr][t] + P->sRed[1][rr][t] + P->sRed[2][rr][t] + bv;
                Hcat[(size_t)(r0 + rr) * G3 + t] = fmaxf(v, 0.f);
            }
        }
        __syncthreads();
    }
    flag_sync(Fp + 96, wgid, t, SF1);
    {
        const float bpa = biasPre[t], bpb = biasPre[576 + t];
        for (int tt = wgid; tt < 256; tt += 96) {
            const int r0 = tt * 8;
            for (int q = t; q < 384; q += 576) {
                int r = q / 48, c4 = q % 48;
                *(float4*)&P->sA[r][4 * c4] = *(const float4*)(Hcat + (size_t)(r0 + r) * G3 + 4 * c4);
            }
            __syncthreads();
            {
                const float* b0 = WpreT + t;
                float a0[8] = {0.f,0.f,0.f,0.f,0.f,0.f,0.f,0.f};
                float a1[8] = {0.f,0.f,0.f,0.f,0.f,0.f,0.f,0.f};
                #pragma unroll 4
                for (int k = 0; k < 192; ++k) {
                    float bva = b0[(size_t)k * G6];
                    float bvb = b0[(size_t)k * G6 + 576];
                    #pragma unroll
                    for (int rr = 0; rr < 8; ++rr) {
                        float av = P->sA[rr][k];
                        a0[rr] += av * bva; a1[rr] += av * bvb;
                    }
                }
                #pragma unroll
                for (int rr = 0; rr < 8; ++rr) {
                    PREg[(size_t)(r0 + rr) * G6 + t]       = a0[rr] + bpa;
                    PREg[(size_t)(r0 + rr) * G6 + 576 + t] = a1[rr] + bpb;
                }
            }
            __syncthreads();
        }
    }
    flag_sync(Fp + 192, wgid, t, SF2);
}

// ---------------------------------------------------------------------------
// Epilogue: 3-layer MLP head. Identical to round 3.
// ---------------------------------------------------------------------------
__device__ void mlp_tail(char* smem, int wgid, int t,
    const float* __restrict__ Hcat,
    const float* __restrict__ mw0, const float* __restrict__ mb0,
    const float* __restrict__ mw1, const float* __restrict__ mb1,
    const float* __restrict__ mw2, const float* __restrict__ mb2,
    float* __restrict__ out, u64* __restrict__ Fd)
{
    if (t < 64) {
        while ((uint32_t)(agload(&Fd[t]) >> 32) != (uint32_t)SDN)
            __builtin_amdgcn_s_sleep(2);
    }
    __syncthreads();
    __threadfence();
    __syncthreads();
    MlpSm* M = (MlpSm*)smem;
    const int c = t % 192, kg = t / 192;
    for (int tt = wgid; tt < 256; tt += 96) {
        const int r0 = tt * 8;
        for (int q = t; q < 1152; q += 576) {
            int r = q / 144, c4 = q % 144;
            *(float4*)&M->sH[r][4 * c4] = *(const float4*)(Hcat + (size_t)(r0 + r) * G3 + 4 * c4);
        }
        __syncthreads();
        {
            const float* bp = mw0 + (size_t)(kg * 192) * 192 + c;
            float acc[8] = {0.f,0.f,0.f,0.f,0.f,0.f,0.f,0.f};
            #pragma unroll 8
            for (int kk = 0; kk < 192; ++kk) {
                float bv = bp[(size_t)kk * 192];
                #pragma unroll
                for (int rr = 0; rr < 8; ++rr) acc[rr] += M->sH[rr][kg * 192 + kk] * bv;
            }
            #pragma unroll
            for (int rr = 0; rr < 8; ++rr) M->sRed[kg][rr][c] = acc[rr];
        }
        __syncthreads();
        if (t < 192) {
            float bv = mb0[t];
            #pragma unroll
            for (int rr = 0; rr < 8; ++rr)
                M->sT[rr][t] = fmaxf(M->sRed[0][rr][t] + M->sRed[1][rr][t] + M->sRed[2][rr][t] + bv, 0.f);
        }
        __syncthreads();
        {
            const float* bp = mw1 + (size_t)(kg * 64) * 192 + c;
            float acc[8] = {0.f,0.f,0.f,0.f,0.f,0.f,0.f,0.f};
            #pragma unroll 8
            for (int kk = 0; kk < 64; ++kk) {
                float bv = bp[(size_t)kk * 192];
                #pragma unroll
                for (int rr = 0; rr < 8; ++rr) acc[rr] += M->sT[rr][kg * 64 + kk] * bv;
            }
            #pragma unroll
            for (int rr = 0; rr < 8; ++rr) M->sRed[kg][rr][c] = acc[rr];
        }
        __syncthreads();
        if (t < 192) {
            float bv = mb1[t];
            #pragma unroll
            for (int rr = 0; rr < 8; ++rr)
                M->sH[rr][t] = fmaxf(M->sRed[0][rr][t] + M->sRed[1][rr][t] + M->sRed[2][rr][t] + bv, 0.f);
        }
        __syncthreads();
        {
            const float* bp = mw2 + (size_t)(kg * 64) * 192 + c;
            float acc[8] = {0.f,0.f,0.f,0.f,0.f,0.f,0.f,0.f};
            #pragma unroll 8
            for (int kk = 0; kk < 64; ++kk) {
                float bv = bp[(size_t)kk * 192];
                #pragma unroll
                for (int rr = 0; rr < 8; ++rr) acc[rr] += M->sH[rr][kg * 64 + kk] * bv;
            }
            #pragma unroll
            for (int rr = 0; rr < 8; ++rr) M->sRed[kg][rr][c] = acc[rr];
        }
        __syncthreads();
        if (t < 192) {
            float bv = mb2[t];
            #pragma unroll
            for (int rr = 0; rr < 8; ++rr)
                out[(size_t)(r0 + rr) * 192 + t] =
                    M->sRed[0][rr][t] + M->sRed[1][rr][t] + M->sRed[2][rr][t] + bv;
        }
        __syncthreads();
    }
}

// ---------------------------------------------------------------------------
// Scan body — round-3 stamped-word transport (best measured), xq removed,
// per-step barriers are LDS-only (no global-store drain).
// ---------------------------------------------------------------------------
template<int ISL2>
__device__ void scan_body(
    ScanSm* S, int b, int w, int t,
    const float* __restrict__ xin, float* __restrict__ hout,
    const float* __restrict__ PREg, const float* __restrict__ adj,
    const float* __restrict__ smask,
    const uint32_t* __restrict__ W4l, const uint32_t* __restrict__ Wr4l,
    const float* __restrict__ gbxl, const float* __restrict__ gatwl,
    uint32_t* __restrict__ Hw, u64* __restrict__ MPsl, u64* __restrict__ Kdl,
    u64* __restrict__ HcW, const u64* __restrict__ HcR,
    const u64* __restrict__ PREcR,
    float* __restrict__ AsB, int sbase)
{
    const int lane = t & 63, wave = t >> 6;
    const int dg0 = w * DS;
    const float* adjB = adj   + (size_t)b * N_ * N_;
    const float* smB  = smask + (size_t)b * N_ * N_;
    const int fi = b * NW;
    const int cB4 = t >> 1, khB4 = t & 1;
    const int w1 = (w + 1) & 3, w2 = (w + 2) & 3, w3 = (w + 3) & 3;

    // Wr -> LDS; Gc weights -> registers
    {
        uint32_t* wr = (uint32_t*)S->Wr4s;
        for (int q = t; q < 9216; q += 576) wr[q] = Wr4l[q];
    }
    uint4 wreg[12];
    {
        const uint4* W4v = (const uint4*)W4l;
        #pragma unroll
        for (int p4 = 0; p4 < 12; ++p4) wreg[p4] = W4v[(12 * khB4 + p4) * GC + cB4];
    }
    float wkv = 0.f, g2b = 0.f, g5b = 0.f;
    if (t < DS) { wkv = gatwl[DH_ + dg0 + t]; g2b = gbxl[dg0 + t]; g5b = gbxl[DH_ + dg0 + t]; }
    if (t < N_) { S->sKsc[t] = 0.f; S->sA0[1][t] = 0.f; S->sA1[1][t] = 0.f; }
    if (t < DS) { S->su0[t] = 0.f; S->su1[t] = 0.f; }
    if (t < 8)  S->sRedS[1][t] = 0.f;
    if (w == 0 && t < N_) AsB[t] = 0.f;

    if (!ISL2) {
        if (t < DS) {
            const float* pre = PREg + (size_t)(b * N_) * G6 + dg0 + t;
            S->sPre[t] = pre[0]; S->sPre[DS + t] = pre[192]; S->sPre[2 * DS + t] = pre[384];
            S->sPre[3 * DS + t] = pre[576]; S->sPre[4 * DS + t] = pre[768]; S->sPre[5 * DS + t] = pre[960];
            S->sXv[t] = xin[(size_t)(b * N_) * G3 + dg0 + t];
        }
        for (int q = t; q < 128; q += 576) {
            if (q < 64)  *(float4*)&S->sAdjN[4 * q] = *(const float4*)(adjB + N_ + 4 * q);
            else { int q2 = q - 64; *(float4*)&S->sSmN[4 * q2] = *(const float4*)(smB + N_ + 4 * q2); }
        }
    } else {
        for (int q = t; q < 320; q += 576) {
            if (q < 64)       *(float4*)&S->sAdjN[4 * q] = *(const float4*)(adjB + N_ + 4 * q);
            else if (q < 128) { int q2 = q - 64;  *(float4*)&S->sSmN[4 * q2] = *(const float4*)(smB + N_ + 4 * q2); }
            else if (q < 176) {
                int d = q - 128;
                const u64* p = HcR + ((size_t)(b * N_) * NW + w) * DS + d;
                u64 v; do { v = agload(p); } while ((uint32_t)(v >> 32) != (uint32_t)STH);
                S->sXv[d] = __uint_as_float((uint32_t)v);
            } else {
                int qq = q - 176;
                const u64* p = PREcR + ((size_t)(b * N_) * NW + w) * 144 + qq;
                u64 v; do { v = agload(p); } while ((uint32_t)(v >> 32) != (uint32_t)STP);
                uint32_t pl = (uint32_t)v;
                S->sPre[2 * qq] = bflo(pl); S->sPre[2 * qq + 1] = bfhi(pl);
            }
        }
    }
    __syncthreads();
    // ---- step 0 (no attention) ----
    {
        float hn = 0.f;
        if (t < DS) {
            float xv = S->sXv[t];
            float r1 = sigm(S->sPre[t]), z1 = sigm(S->sPre[DS + t]);
            float n1 = tanhf_(S->sPre[2 * DS + t] + r1 * g2b);
            float Cv = (1.f - z1) * n1;
            float r2 = sigm(S->sPre[3 * DS + t]), z2 = sigm(S->sPre[4 * DS + t]);
            float n2 = tanhf_(g5b + r2 * S->sPre[5 * DS + t]);
            hn = Cv + (1.f - z2) * n2 + z2 * xv;
            S->sHn[t] = hn;
            hout[(size_t)(b * N_) * G3 + dg0 + t] = hn;
            if (!ISL2) HcW[((size_t)(b * N_) * NW + w) * DS + t] = packvs(hn, STH);
        }
        if (t == 0) { S->sSavedA[1] = S->sAdjN[0]; S->sSavedS[1] = S->sSmN[0]; }
        if (wave == 0) {
            float v = hn * wkv;
            #pragma unroll
            for (int o = 32; o; o >>= 1) v += __shfl_xor(v, o);
            if (lane == 0) { S->sSaved[6] = v; agstore(&Kdl[fi + w], packvs(v, sbase)); }  // parity 0
        }
    }
    __syncthreads();
    if (t < KD) Hw[(size_t)t * N_] = f2bf(S->sHn[2 * t]) | (f2bf(S->sHn[2 * t + 1]) << 16);
    __syncthreads();

    for (int i = 1; i < N_; ++i) {
        const int row = b * N_ + i;
        const int stamp = sbase + i;
        const int pp = i & 1, pn = pp ^ 1;

        // ---- P1: raw partials + stamped send; prefetch ----------------------
        if (t < DH_) {
            float rr = 0.f, p0 = 0.f, p1 = 0.f;
            #pragma unroll 4
            for (int kq = 0; kq < 12; ++kq) {
                uint4 wv = S->Wr4s[kq * DH_ + t];
                const int k0 = 4 * kq;
                float lo, hi;
                lo = bflo(wv.x); hi = bfhi(wv.x);
                rr = fmaf(S->su0[k0 + 0], lo, rr); rr = fmaf(S->su1[k0 + 0], hi, rr);
                p0 = fmaf(S->sHn[k0 + 0], lo, p0); p1 = fmaf(S->sHn[k0 + 0], hi, p1);
                lo = bflo(wv.y); hi = bfhi(wv.y);
                rr = fmaf(S->su0[k0 + 1], lo, rr); rr = fmaf(S->su1[k0 + 1], hi, rr);
                p0 = fmaf(S->sHn[k0 + 1], lo, p0); p1 = fmaf(S->sHn[k0 + 1], hi, p1);
                lo = bflo(wv.z); hi = bfhi(wv.z);
                rr = fmaf(S->su0[k0 + 2], lo, rr); rr = fmaf(S->su1[k0 + 2], hi, rr);
                p0 = fmaf(S->sHn[k0 + 2], lo, p0); p1 = fmaf(S->sHn[k0 + 2], hi, p1);
                lo = bflo(wv.w); hi = bfhi(wv.w);
                rr = fmaf(S->su0[k0 + 3], lo, rr); rr = fmaf(S->su1[k0 + 3], hi, rr);
                p0 = fmaf(S->sHn[k0 + 3], lo, p0); p1 = fmaf(S->sHn[k0 + 3], hi, p1);
            }
            S->sRl[t] = rr; S->sP0l[t] = p0; S->sP1l[t] = p1;
            u64* base = &MPsl[(size_t)pp * MPSZ + ((size_t)(fi + w) * DH_ + t) * 3];
            agstore(base + 0, packvs(rr, stamp));
            agstore(base + 1, packvs(p0, stamp));
            agstore(base + 2, packvs(p1, stamp));
        } else if (t >= 384) {
            const int u = t - 384;
            const int inx = (i + 1 < N_) ? i + 1 : N_ - 1;
            if (!ISL2) {
                for (int qq = u; qq < 212; qq += 192) {
                    if (qq < 64)
                        *(float4*)&S->sAdjN[4 * qq] = *(const float4*)(adjB + (size_t)inx * N_ + 4 * qq);
                    else if (qq < 128) { int q2 = qq - 64;
                        *(float4*)&S->sSmN[4 * q2] = *(const float4*)(smB + (size_t)inx * N_ + 4 * q2); }
                    else if (qq < 140) { int q2 = qq - 128;
                        *(float4*)&S->sXv[4 * q2] = *(const float4*)(xin + (size_t)row * G3 + dg0 + 4 * q2); }
                    else { int q2 = qq - 140; int g = q2 / 12, o = q2 - 12 * g;
                        *(float4*)&S->sPre[g * DS + 4 * o] =
                            *(const float4*)(PREg + (size_t)row * G6 + g * DH_ + dg0 + 4 * o); }
                }
            } else {
                for (int qq = u; qq < 320; qq += 192) {
                    if (qq < 64)
                        *(float4*)&S->sAdjN[4 * qq] = *(const float4*)(adjB + (size_t)inx * N_ + 4 * qq);
                    else if (qq < 128) { int q2 = qq - 64;
                        *(float4*)&S->sSmN[4 * q2] = *(const float4*)(smB + (size_t)inx * N_ + 4 * q2); }
                    else if (qq < 176) {
                        int d = qq - 128;
                        const u64* p = HcR + ((size_t)row * NW + w) * DS + d;
                        u64 v; do { v = agload(p); } while ((uint32_t)(v >> 32) != (uint32_t)(STH + i));
                        S->sXv[d] = __uint_as_float((uint32_t)v);
                    } else {
                        int q2 = qq - 176;
                        const u64* p = PREcR + ((size_t)row * NW + w) * 144 + q2;
                        u64 v; do { v = agload(p); } while ((uint32_t)(v >> 32) != (uint32_t)(STP + i));
                        uint32_t pl = (uint32_t)v;
                        S->sPre[2 * q2] = bflo(pl); S->sPre[2 * q2 + 1] = bfhi(pl);
                    }
                }
            }
        }
        wg_barrier();                                            // B1

        // ---- P2: E(i+1) weights for j <= i-2 --------------------------------
        if (t < N_) {
            float e = 0.f;
            if (t == i) { S->sSavedA[pn] = S->sAdjN[t]; S->sSavedS[pn] = S->sSmN[t]; }
            if (t < i - 1 && S->sAdjN[t] > 0.5f) e = __expf(S->sKsc[t]);
            float b0 = e * S->sSmN[t];
            S->sA0[pn][t] = b0; S->sA1[pn][t] = e - b0;
            float ps = e;
            #pragma unroll
            for (int o = 32; o; o >>= 1) ps += __shfl_xor(ps, o);
            if (lane == 0) S->sRedS[pn][wave] = ps;
        }
        wg_barrier();                                            // B2

        // ---- P3: U(i+1) matvec || stamped 9-addr poll + kdot ----------------
        if (t < 384) {
            const int ilim = i - 1;                              // j <= i-2
            const int kd = t >> 4, jp = t & 15;
            const uint32_t* hp = Hw + (size_t)kd * N_;
            float u0l = 0.f, u0h = 0.f, u1l = 0.f, u1h = 0.f;
            int j = jp;
            while (j + 48 < ilim) {
                uint32_t h0 = hp[j], h1 = hp[j + 16], h2 = hp[j + 32], h3 = hp[j + 48];
                float b0, b1;
                b0 = S->sA0[pn][j];      b1 = S->sA1[pn][j];
                u0l = fmaf(b0, bflo(h0), u0l); u0h = fmaf(b0, bfhi(h0), u0h);
                u1l = fmaf(b1, bflo(h0), u1l); u1h = fmaf(b1, bfhi(h0), u1h);
                b0 = S->sA0[pn][j + 16]; b1 = S->sA1[pn][j + 16];
                u0l = fmaf(b0, bflo(h1), u0l); u0h = fmaf(b0, bfhi(h1), u0h);
                u1l = fmaf(b1, bflo(h1), u1l); u1h = fmaf(b1, bfhi(h1), u1h);
                b0 = S->sA0[pn][j + 32]; b1 = S->sA1[pn][j + 32];
                u0l = fmaf(b0, bflo(h2), u0l); u0h = fmaf(b0, bfhi(h2), u0h);
                u1l = fmaf(b1, bflo(h2), u1l); u1h = fmaf(b1, bfhi(h2), u1h);
                b0 = S->sA0[pn][j + 48]; b1 = S->sA1[pn][j + 48];
                u0l = fmaf(b0, bflo(h3), u0l); u0h = fmaf(b0, bfhi(h3), u0h);
                u1l = fmaf(b1, bflo(h3), u1l); u1h = fmaf(b1, bfhi(h3), u1h);
                j += 64;
            }
            for (; j < ilim; j += 16) {
                uint32_t hv = hp[j];
                float b0 = S->sA0[pn][j], b1 = S->sA1[pn][j];
                u0l = fmaf(b0, bflo(hv), u0l); u0h = fmaf(b0, bfhi(hv), u0h);
                u1l = fmaf(b1, bflo(hv), u1l); u1h = fmaf(b1, bfhi(hv), u1h);
            }
            #pragma unroll
            for (int o = 1; o <= 8; o <<= 1) {
                u0l += __shfl_xor(u0l, o); u0h += __shfl_xor(u0h, o);
                u1l += __shfl_xor(u1l, o); u1h += __shfl_xor(u1h, o);
            }
            if (jp == 0) {
                S->su0[2 * kd] = u0l; S->su0[2 * kd + 1] = u0h;
                S->su1[2 * kd] = u1l; S->su1[2 * kd + 1] = u1h;
            }
        } else {
            const int d = t - 384;
            const u64* pA = &MPsl[(size_t)pp * MPSZ + ((size_t)(fi + w1) * DH_ + d) * 3];
            const u64* pB = &MPsl[(size_t)pp * MPSZ + ((size_t)(fi + w2) * DH_ + d) * 3];
            const u64* pC = &MPsl[(size_t)pp * MPSZ + ((size_t)(fi + w3) * DH_ + d) * 3];
            const uint32_t ex = (uint32_t)stamp;
            u64 a0, a1, a2, b0, b1, b2, c0, c1, c2;
            do {
                a0 = agload(pA); a1 = agload(pA + 1); a2 = agload(pA + 2);
                b0 = agload(pB); b1 = agload(pB + 1); b2 = agload(pB + 2);
                c0 = agload(pC); c1 = agload(pC + 1); c2 = agload(pC + 2);
            } while ((uint32_t)(a0 >> 32) != ex || (uint32_t)(a1 >> 32) != ex ||
                     (uint32_t)(a2 >> 32) != ex || (uint32_t)(b0 >> 32) != ex ||
                     (uint32_t)(b1 >> 32) != ex || (uint32_t)(b2 >> 32) != ex ||
                     (uint32_t)(c0 >> 32) != ex || (uint32_t)(c1 >> 32) != ex ||
                     (uint32_t)(c2 >> 32) != ex);
            S->sRl[d]  += u2f(a0) + u2f(b0) + u2f(c0);
            S->sP0l[d] += u2f(a1) + u2f(b1) + u2f(c1);
            S->sP1l[d] += u2f(a2) + u2f(b2) + u2f(c2);
            if (t == 575) {
                const uint32_t ex2 = (uint32_t)(stamp - 1);
                const int kpar = (i - 1) & 1;
                u64 k0, k1, k2;
                u64* q1 = &Kdl[kpar * KDSZ + fi + w1];
                u64* q2 = &Kdl[kpar * KDSZ + fi + w2];
                u64* q3 = &Kdl[kpar * KDSZ + fi + w3];
                do {
                    k0 = agload(q1); k1 = agload(q2); k2 = agload(q3);
                } while ((uint32_t)(k0 >> 32) != ex2 || (uint32_t)(k1 >> 32) != ex2 ||
                         (uint32_t)(k2 >> 32) != ex2);
                float kdot = S->sSaved[6] + u2f(k0) + u2f(k1) + u2f(k2);
                float adj1 = S->sSavedA[pp], sm1 = S->sSavedS[pp];
                float er = __expf(kdot);
                float e1 = (adj1 > 0.5f) ? er : 0.f;
                float Ssum = S->sRedS[pp][0] + S->sRedS[pp][1] + S->sRedS[pp][2]
                           + S->sRedS[pp][3] + S->sRedS[pp][4] + e1;
                S->sKsc[i - 1] = kdot;
                float invS = 1.f / Ssum;
                float e1c0 = e1 * sm1, e1c1 = e1 - e1c0;
                S->sSaved[2] = invS;
                S->sSaved[4] = e1c0; S->sSaved[5] = e1c1;
                S->sA0[pp][i - 1] = e1c0; S->sA1[pp][i - 1] = e1c1;
                // append j = i-1 term for query i+1
                float adjn = S->sAdjN[i - 1], smn = S->sSmN[i - 1];
                float en = (adjn > 0.5f) ? er : 0.f;
                float n0 = en * smn;
                S->sA0[pn][i - 1] = n0; S->sA1[pn][i - 1] = en - n0;
                S->sRedS[pn][4] = en;
            }
        }
        wg_barrier();                                            // B3

        // ---- P4: final M combine; su append; AsB row i ----------------------
        if (t < DH_) {
            S->sM[t] = (S->sRl[t] + S->sSaved[4] * S->sP0l[t]
                                  + S->sSaved[5] * S->sP1l[t]) * S->sSaved[2];
        } else if (t < 192 + DS) {
            const int k = t - 192;
            float a0 = S->sA0[pn][i - 1], a1 = S->sA1[pn][i - 1];
            S->su0[k] += a0 * S->sHn[k];
            S->su1[k] += a1 * S->sHn[k];
        } else if (w == 0 && t >= 256 && t < 512) {
            const int j = t - 256;
            AsB[(size_t)i * N_ + j] = (S->sA0[pp][j] + S->sA1[pp][j]) * S->sSaved[2];
        }
        wg_barrier();                                            // B4

        // ---- P5: Gc from register-resident weights --------------------------
        {
            float g = 0.f;
            #pragma unroll
            for (int p4 = 0; p4 < 12; ++p4) {
                const uint4 wv = wreg[p4];
                const int m0 = 8 * (12 * khB4 + p4);
                g = fmaf(S->sM[m0 + 0], bflo(wv.x), g); g = fmaf(S->sM[m0 + 1], bfhi(wv.x), g);
                g = fmaf(S->sM[m0 + 2], bflo(wv.y), g); g = fmaf(S->sM[m0 + 3], bfhi(wv.y), g);
                g = fmaf(S->sM[m0 + 4], bflo(wv.z), g); g = fmaf(S->sM[m0 + 5], bfhi(wv.z), g);
                g = fmaf(S->sM[m0 + 6], bflo(wv.w), g); g = fmaf(S->sM[m0 + 7], bfhi(wv.w), g);
            }
            g += __shfl_xor(g, 1);
            if (khB4 == 0) S->sGc[cB4] = g;
        }
        wg_barrier();                                            // B5

        // ---- P6: gates -> hn(i); Hc store; Kd stamped store; Hw pack --------
        {
            float hn = 0.f;
            if (t < DS) {
                float Mv = S->sM[dg0 + t];
                float r1 = sigm(S->sPre[t] + S->sGc[t]);
                float z1 = sigm(S->sPre[DS + t] + S->sGc[DS + t]);
                float n1 = tanhf_(S->sPre[2 * DS + t] + r1 * (S->sGc[2 * DS + t] + g2b));
                float Cv = (1.f - z1) * n1 + z1 * Mv;
                float r2 = sigm(S->sGc[3 * DS + t] + S->sPre[3 * DS + t]);
                float z2 = sigm(S->sGc[4 * DS + t] + S->sPre[4 * DS + t]);
                float n2 = tanhf_(S->sGc[5 * DS + t] + g5b + r2 * S->sPre[5 * DS + t]);
                hn = Cv + (1.f - z2) * n2 + z2 * S->sXv[t];
                S->sHn[t] = hn;
                hout[(size_t)row * G3 + dg0 + t] = hn;
                if (!ISL2) HcW[((size_t)row * NW + w) * DS + t] = packvs(hn, STH + i);
            }
            if (wave == 0) {
                float v = hn * wkv;
                #pragma unroll
                for (int o = 32; o; o >>= 1) v += __shfl_xor(v, o);
                if (lane == 0) { S->sSaved[6] = v; agstore(&Kdl[pp * KDSZ + fi + w], packvs(v, stamp)); }
            }
            if (t < KD) Hw[(size_t)t * N_ + i] = f2bf(S->sHn[2 * t]) | (f2bf(S->sHn[2 * t + 1]) << 16);
        }
        wg_barrier();                                            // B6
    }
}

// ---------------------------------------------------------------------------
// PRE worker — xq removed; LDS-only barriers.
// ---------------------------------------------------------------------------
__device__ void worker_body(WorkSm* Wm, int b, int w, int t,
    const uint32_t* __restrict__ Wp4g, const float* __restrict__ bias2,
    const u64* __restrict__ HcR, u64* __restrict__ PREcW)
{
    const int c = t >> 1, kh = t & 1;
    uint4 wpreg[12];
    {
        const uint4* v4 = (const uint4*)Wp4g;
        #pragma unroll
        for (int p4 = 0; p4 < 12; ++p4) wpreg[p4] = v4[(12 * kh + p4) * GC + c];
    }
    float bv = 0.f;
    if (kh == 0) bv = bias2[192 * (c / DS) + w * DS + (c % DS)];
    for (int i = 0; i < N_; ++i) {
        if (t < DH_) {
            const u64* p = HcR + ((size_t)(b * N_ + i) * NW + (t / DS)) * DS + (t % DS);
            u64 v; do { v = agload(p); } while ((uint32_t)(v >> 32) != (uint32_t)(STH + i));
            Wm->sX[t] = __uint_as_float((uint32_t)v);
        }
        wg_barrier();
        {
            float g = 0.f;
            #pragma unroll
            for (int p4 = 0; p4 < 12; ++p4) {
                const uint4 wv = wpreg[p4];
                const int m0 = 8 * (12 * kh + p4);
                g = fmaf(Wm->sX[m0 + 0], bflo(wv.x), g); g = fmaf(Wm->sX[m0 + 1], bfhi(wv.x), g);
                g = fmaf(Wm->sX[m0 + 2], bflo(wv.y), g); g = fmaf(Wm->sX[m0 + 3], bfhi(wv.y), g);
                g = fmaf(Wm->sX[m0 + 4], bflo(wv.z), g); g = fmaf(Wm->sX[m0 + 5], bfhi(wv.z), g);
                g = fmaf(Wm->sX[m0 + 6], bflo(wv.w), g); g = fmaf(Wm->sX[m0 + 7], bfhi(wv.w), g);
            }
            g += __shfl_xor(g, 1);
            if (kh == 0) Wm->sPv[c] = g + bv;
        }
        wg_barrier();
        if (t < 144) {
            u64 v = ((u64)(uint32_t)(STP + i) << 32)
                  | f2bf(Wm->sPv[2 * t]) | (f2bf(Wm->sPv[2 * t + 1]) << 16);
            agstore(&PREcW[((size_t)(b * N_ + i) * NW + w) * 144 + t], v);
        }
        wg_barrier();
    }
}

// ---------------------------------------------------------------------------
// Single fused kernel.
// ---------------------------------------------------------------------------
__global__ __launch_bounds__(576, 1) void pipeline_kernel(
    const float* __restrict__ features, const float* __restrict__ fc1_w,
    const float* __restrict__ fc1_b,
    const float* __restrict__ adj, const float* __restrict__ smask,
    const float* __restrict__ gatw,
    const float* __restrict__ wr0, const float* __restrict__ wr1,
    const float* __restrict__ c_wih, const float* __restrict__ c_whh,
    const float* __restrict__ c_bih, const float* __restrict__ c_bhh,
    const float* __restrict__ p_wih, const float* __restrict__ p_whh,
    const float* __restrict__ p_bih, const float* __restrict__ p_bhh,
    const float* __restrict__ mw0, const float* __restrict__ mb0,
    const float* __restrict__ mw1, const float* __restrict__ mb1,
    const float* __restrict__ mw2, const float* __restrict__ mb2,
    float* __restrict__ Hcat, float* __restrict__ PREg,
    float* __restrict__ WpreT, uint32_t* __restrict__ W4,
    uint32_t* __restrict__ Wr4, uint32_t* __restrict__ Wp4w,
    float* __restrict__ biasPre, float* __restrict__ gbx,
    uint32_t* __restrict__ Hb, u64* __restrict__ MPs, u64* __restrict__ Kd,
    u64* __restrict__ Hc, u64* __restrict__ PREc,
    u64* __restrict__ Fp, u64* __restrict__ Fd,
    float* __restrict__ out)
{
    __shared__ __align__(16) char smem[sizeof(SmemAll)];
    const int blk = blockIdx.x, t = threadIdx.x;
    const int wgid = blk;
    const int b = blk & 7, r12 = blk >> 3;
    const int role = r12 >> 2, w = r12 & 3;

    // ---- prepack slices (all WGs) ------------------------------------------
    for (int j = 0; j < 4; ++j) {
        int idx = wgid * 576 + t + 55296 * j;
        prepack_slice(idx, wr0, wr1, c_wih, c_whh, c_bih, c_bhh,
                      p_wih, p_whh, p_bih, p_bhh,
                      WpreT, W4, Wr4, Wp4w, biasPre, gbx);
    }
    flag_sync(Fp, wgid, t, SPK);

    // ---- fc1 + PRE-l1 prologue ---------------------------------------------
    prologue(smem, wgid, t, features, fc1_w, fc1_b, WpreT, biasPre,
             Hcat, PREg, Fp);

    // ---- roles -------------------------------------------------------------
    float* As = out + 393216;
    if (role == 0) {
        scan_body<0>((ScanSm*)smem, b, w, t,
            Hcat, Hcat + 192, PREg, adj, smask,
            W4, Wr4, gbx, gatw,
            Hb + (size_t)(b * NW + w) * KD * N_, MPs, Kd,
            Hc, nullptr, nullptr,
            As + (size_t)b * (L_ * N_ * N_), 1);
        __threadfence();
        __syncthreads();
        if (t == 0) agstore(&Fd[b * 8 + w], packvs(0.f, SDN));
    } else if (role == 2) {
        scan_body<1>((ScanSm*)smem, b, w, t,
            nullptr, Hcat + 384, nullptr, adj, smask,
            W4 + NW * 27648, Wr4 + NW * 9216, gbx + 384, gatw + 384,
            Hb + (size_t)(32 + b * NW + w) * KD * N_,
            MPs + (size_t)2 * MPSZ, Kd + 2 * KDSZ,
            nullptr, Hc, PREc,
            As + (size_t)b * (L_ * N_ * N_) + N_ * N_, 30001);
        __threadfence();
        __syncthreads();
        if (t == 0) agstore(&Fd[b * 8 + 4 + w], packvs(0.f, SDN));
    } else {
        worker_body((WorkSm*)smem, b, w, t,
            Wp4w + (size_t)w * 27648, biasPre + G6,
            Hc, PREc);
    }

    // ---- MLP epilogue (all WGs) --------------------------------------------
    mlp_tail(smem, wgid, t, Hcat, mw0, mb0, mw1, mb1, mw2, mb2, out, Fd);
}

// ---------------------------------------------------------------------------
extern "C" void kernel_launch(void* const* d_in, const int* in_sizes, int n_in,
                              void* d_out, int out_size, void* d_ws, size_t ws_size,
                              hipStream_t stream)
{
    const float* features = (const float*)d_in[0];
    const float* adj      = (const float*)d_in[1];
    const float* smask    = (const float*)d_in[2];
    const float* fc1_w = (const float*)d_in[5];
    const float* fc1_b = (const float*)d_in[6];
    const float* gat_w = (const float*)d_in[7];
    const float* wr0   = (const float*)d_in[9];
    const float* wr1   = (const float*)d_in[10];
    const float* c_wih = (const float*)d_in[11];
    const float* c_whh = (const float*)d_in[12];
    const float* c_bih = (const float*)d_in[13];
    const float* c_bhh = (const float*)d_in[14];
    const float* p_wih = (const float*)d_in[15];
    const float* p_whh = (const float*)d_in[16];
    const float* p_bih = (const float*)d_in[17];
    const float* p_bhh = (const float*)d_in[18];
    const float* mw0 = (const float*)d_in[19];
    const float* mb0 = (const float*)d_in[20];
    const float* mw1 = (const float*)d_in[21];
    const float* mb1 = (const float*)d_in[22];
    const float* mw2 = (const float*)d_in[23];
    const float* mb2 = (const float*)d_in[24];
    float* out = (float*)d_out;

    char* wsb = (char*)d_ws;
    size_t off = 0;
    auto carve = [&](size_t bytes) -> char* {
        char* p = wsb + off;
        off = (off + bytes + 255) & ~(size_t)255;
        return p;
    };
    float* Hcat     = (float*)carve(2048ull * 576 * 4);
    float* PREg     = (float*)carve(2048ull * 1152 * 4);
    float* WpreT    = (float*)carve(192ull * 1152 * 4);
    uint32_t* W4    = (uint32_t*)carve(2ull * NW * 27648 * 4);
    uint32_t* Wr4   = (uint32_t*)carve(2ull * NW * 9216 * 4);
    uint32_t* Wp4w  = (uint32_t*)carve((size_t)NW * 27648 * 4);
    float* biasPre  = (float*)carve(2ull * 1152 * 4);
    float* gbx      = (float*)carve(2ull * 384 * 4);
    uint32_t* Hb    = (uint32_t*)carve(64ull * KD * 256 * 4);
    u64* MPs        = (u64*)carve(4ull * MPSZ * 8);      // 2 roles x 2 parities
    u64* Kd         = (u64*)carve(4ull * KDSZ * 8);      // 2 roles x 2 parities
    u64* Hc         = (u64*)carve(8ull * 256 * NW * DS * 8);
    u64* PREc       = (u64*)carve(8ull * 256 * NW * 144 * 8);
    u64* Fp         = (u64*)carve(288ull * 8);
    u64* Fd         = (u64*)carve(64ull * 8);

    pipeline_kernel<<<dim3(96), 576, 0, stream>>>(
        features, fc1_w, fc1_b, adj, smask, gat_w,
        wr0, wr1, c_wih, c_whh, c_bih, c_bhh, p_wih, p_whh, p_bih, p_bhh,
        mw0, mb0, mw1, mb1, mw2, mb2,
        Hcat, PREg, WpreT, W4, Wr4, Wp4w, biasPre, gbx,
        Hb, MPs, Kd, Hc, PREc, Fp, Fd, out);
}